// Round 1
// baseline (1432.161 us; speedup 1.0000x reference)
//
#include <hip/hip_runtime.h>
#include <math.h>

#define SEQL 2048
#define BATCH 1024

// ---------------------------------------------------------------------------
// Generic NT GEMM: C[i][j] = sum_k opA(A[i][k]) * B[j][k]
// 64x64 tile, BK=32, 256 threads, 4x4 register blocking.
// FUSE: opA(a) = relu(sA[k]*a + tA[k])  (BN+ReLU fused on the K axis of A)
// M, N assumed multiples of 64; K arbitrary (zero-padded tail).
// ---------------------------------------------------------------------------
template<bool FUSE>
__global__ __launch_bounds__(256) void gemm_nt(
    const float* __restrict__ A, int lda,
    const float* __restrict__ B, int ldb,
    float* __restrict__ C, int ldc,
    int M, int N, int K,
    const float* __restrict__ sA, const float* __restrict__ tA)
{
    __shared__ float As[32][68];   // [k][m], padded so rows are 16B aligned
    __shared__ float Bs[32][68];   // [k][n]

    const int tid = threadIdx.x;
    const int tx = tid & 15;       // n-dir (4 outputs)
    const int ty = tid >> 4;       // m-dir (4 outputs)
    const int n0 = blockIdx.x * 64;
    const int m0 = blockIdx.y * 64;

    const int kk0 = tid & 31;      // k index for loading
    const int rr0 = tid >> 5;      // 0..7 row group for loading

    float acc[4][4] = {};

    const int ktiles = (K + 31) >> 5;
    for (int kt = 0; kt < ktiles; ++kt) {
        const int kg = kt * 32 + kk0;
        const bool kin = (kg < K);
        float sv = 0.f, tv = 0.f;
        if (FUSE && kin) { sv = sA[kg]; tv = tA[kg]; }
        #pragma unroll
        for (int r = 0; r < 8; ++r) {
            const int m = rr0 + r * 8;
            float a = 0.f, b = 0.f;
            if (kin) {
                a = A[(size_t)(m0 + m) * lda + kg];
                if (FUSE) a = fmaxf(sv * a + tv, 0.f);
                b = B[(size_t)(n0 + m) * ldb + kg];
            }
            As[kk0][m] = a;
            Bs[kk0][m] = b;
        }
        __syncthreads();
        #pragma unroll
        for (int kk = 0; kk < 32; ++kk) {
            const float4 a4 = *reinterpret_cast<const float4*>(&As[kk][ty * 4]);
            const float4 b4 = *reinterpret_cast<const float4*>(&Bs[kk][tx * 4]);
            const float av[4] = {a4.x, a4.y, a4.z, a4.w};
            const float bv[4] = {b4.x, b4.y, b4.z, b4.w};
            #pragma unroll
            for (int i = 0; i < 4; ++i)
                #pragma unroll
                for (int j = 0; j < 4; ++j)
                    acc[i][j] += av[i] * bv[j];
        }
        __syncthreads();
    }

    #pragma unroll
    for (int i = 0; i < 4; ++i) {
        float4 o;
        o.x = acc[i][0]; o.y = acc[i][1]; o.z = acc[i][2]; o.w = acc[i][3];
        *reinterpret_cast<float4*>(&C[(size_t)(m0 + ty * 4 + i) * ldc + n0 + tx * 4]) = o;
    }
}

// ---------------------------------------------------------------------------
// Column-wise batchnorm stats over `rows` rows: emit scale/shift so that
// bn(x) = s[c]*x + t[c].  One block per 64 columns, 4 row-groups.
// ---------------------------------------------------------------------------
__global__ __launch_bounds__(256) void bn_stats(
    const float* __restrict__ X, int rows, int ld,
    const float* __restrict__ g, const float* __restrict__ b,
    float* __restrict__ s, float* __restrict__ t)
{
    __shared__ float rsum[4][64];
    __shared__ float rsq[4][64];
    const int tid = threadIdx.x;
    const int c = tid & 63;
    const int rg = tid >> 6;
    const int col = blockIdx.x * 64 + c;

    float sum = 0.f, sq = 0.f;
    for (int r = rg; r < rows; r += 4) {
        const float v = X[(size_t)r * ld + col];
        sum += v;
        sq += v * v;
    }
    rsum[rg][c] = sum;
    rsq[rg][c] = sq;
    __syncthreads();
    if (rg == 0) {
        sum = rsum[0][c] + rsum[1][c] + rsum[2][c] + rsum[3][c];
        sq  = rsq[0][c]  + rsq[1][c]  + rsq[2][c]  + rsq[3][c];
        const float inv = 1.0f / (float)rows;
        const float mean = sum * inv;
        const float var = fmaxf(sq * inv - mean * mean, 0.f);
        const float rstd = 1.0f / sqrtf(var + 1e-5f);
        const float sv = g[col] * rstd;
        s[col] = sv;
        t[col] = b[col] - mean * sv;
    }
}

// ---------------------------------------------------------------------------
// Mamba scan. One 32-lane half-wave per batch row; lane = (e,n) state element.
// Reads C1 (pre-BN GEMM1 output), applies BN via (s1,t1) on the fly, runs the
// full per-step pipeline (conv -> silu -> x_dbl -> softplus -> SSM step),
// writes the mamba output IN PLACE over C1.
// ---------------------------------------------------------------------------
__global__ __launch_bounds__(256) void mamba_scan(
    float* __restrict__ Y,
    const float* __restrict__ s1, const float* __restrict__ t1,
    const float* __restrict__ Win, const float* __restrict__ convw,
    const float* __restrict__ convb, const float* __restrict__ Wx,
    const float* __restrict__ Wdt, const float* __restrict__ bdt,
    const float* __restrict__ Alog, const float* __restrict__ Dp,
    const float* __restrict__ Wout)
{
    const int tid = threadIdx.x;
    const int wave = tid >> 6;
    const int lane = tid & 63;
    const int half = lane >> 5;
    const int l5 = lane & 31;
    const int e = l5 >> 4;
    const int n = l5 & 15;
    const int row = blockIdx.x * 8 + wave * 2 + half;

    const float wi0 = Win[0], wi1 = Win[1];
    const float wze = Win[2 + e];
    const float cw00 = convw[0], cw01 = convw[1], cw02 = convw[2], cw03 = convw[3];
    const float cw10 = convw[4], cw11 = convw[5], cw12 = convw[6], cw13 = convw[7];
    const float cb0 = convb[0], cb1 = convb[1];
    const float wx00 = Wx[0], wx01 = Wx[1];
    const float wxB0 = Wx[(1 + n) * 2 + 0], wxB1 = Wx[(1 + n) * 2 + 1];
    const float wxC0 = Wx[(17 + n) * 2 + 0], wxC1 = Wx[(17 + n) * 2 + 1];
    const float wdte = Wdt[e], bdte = bdt[e];
    const float Aen = -__expf(Alog[e * 16 + n]);
    const float De = Dp[e], woute = Wout[e];

    float* yrow = Y + (size_t)row * SEQL;

    float h = 0.f;
    // pre-conv x history: a = l-1, b = l-2, c = l-3 (zero padded)
    float h0a = 0.f, h0b = 0.f, h0c = 0.f;
    float h1a = 0.f, h1b = 0.f, h1c = 0.f;

    #pragma unroll 4
    for (int l = 0; l < SEQL; ++l) {
        const float u = s1[l] * yrow[l] + t1[l];
        const float x0 = u * wi0;
        const float x1 = u * wi1;
        // causal depthwise conv, cross-correlation: out[l] = sum_k w[k]*x[l-3+k]
        const float cv0 = cw00 * h0c + cw01 * h0b + cw02 * h0a + cw03 * x0 + cb0;
        const float cv1 = cw10 * h1c + cw11 * h1b + cw12 * h1a + cw13 * x1 + cb1;
        h0c = h0b; h0b = h0a; h0a = x0;
        h1c = h1b; h1b = h1a; h1a = x1;
        const float xs0 = cv0 / (1.f + __expf(-cv0));
        const float xs1 = cv1 / (1.f + __expf(-cv1));
        const float d0 = xs0 * wx00 + xs1 * wx01;
        const float pre = d0 * wdte + bdte;
        const float dt = __logf(1.f + __expf(pre));        // softplus
        const float Bn = xs0 * wxB0 + xs1 * wxB1;
        const float Cn = xs0 * wxC0 + xs1 * wxC1;
        const float dA = __expf(dt * Aen);
        const float xse = e ? xs1 : xs0;
        h = h * dA + (dt * xse) * Bn;
        float py = h * Cn;
        py += __shfl_xor(py, 1);
        py += __shfl_xor(py, 2);
        py += __shfl_xor(py, 4);
        py += __shfl_xor(py, 8);
        const float ye = py + De * xse;
        const float z = u * wze;
        const float sz = (z / (1.f + __expf(-z))) * woute;
        float tt = ye * sz;
        tt += __shfl_xor(tt, 16);
        if (l5 == 0) yrow[l] = tt;
    }
}

// ---------------------------------------------------------------------------
extern "C" void kernel_launch(void* const* d_in, const int* in_sizes, int n_in,
                              void* d_out, int out_size, void* d_ws, size_t ws_size,
                              hipStream_t stream)
{
    const float* x     = (const float*)d_in[0];   // [1024][1775]
    const float* W1    = (const float*)d_in[1];   // [2048][1775]
    const float* g1    = (const float*)d_in[2];   // [2048]
    const float* b1    = (const float*)d_in[3];   // [2048]
    const float* Win   = (const float*)d_in[4];   // [4][1]
    const float* convw = (const float*)d_in[5];   // [2][1][4]
    const float* convb = (const float*)d_in[6];   // [2]
    const float* Wx    = (const float*)d_in[7];   // [33][2]
    const float* Wdt   = (const float*)d_in[8];   // [2][1]
    const float* bdt   = (const float*)d_in[9];   // [2]
    const float* Alog  = (const float*)d_in[10];  // [2][16]
    const float* Dp    = (const float*)d_in[11];  // [2]
    const float* Wout  = (const float*)d_in[12];  // [1][2]
    const float* W2    = (const float*)d_in[13];  // [512][2048]
    const float* g2    = (const float*)d_in[14];  // [512]
    const float* b2    = (const float*)d_in[15];  // [512]
    const float* W3    = (const float*)d_in[16];  // [256][512]

    float* C1 = (float*)d_ws;                  // [1024][2048], becomes mamba out
    float* h2 = C1 + (size_t)BATCH * SEQL;     // [1024][512]
    float* s1 = h2 + (size_t)BATCH * 512;      // [2048]
    float* t1 = s1 + SEQL;                     // [2048]
    float* s2 = t1 + SEQL;                     // [512]
    float* t2 = s2 + 512;                      // [512]

    // 1) C1 = x @ W1^T
    gemm_nt<false><<<dim3(SEQL / 64, BATCH / 64), 256, 0, stream>>>(
        x, 1775, W1, 1775, C1, SEQL, BATCH, SEQL, 1775, nullptr, nullptr);

    // 2) BN1 stats -> scale/shift
    bn_stats<<<SEQL / 64, 256, 0, stream>>>(C1, BATCH, SEQL, g1, b1, s1, t1);

    // 3) mamba scan (in place over C1)
    mamba_scan<<<BATCH / 8, 256, 0, stream>>>(C1, s1, t1, Win, convw, convb,
                                              Wx, Wdt, bdt, Alog, Dp, Wout);

    // 4) h2 = mamba_out @ W2^T
    gemm_nt<false><<<dim3(512 / 64, BATCH / 64), 256, 0, stream>>>(
        C1, SEQL, W2, SEQL, h2, 512, BATCH, 512, SEQL, nullptr, nullptr);

    // 5) BN2 stats
    bn_stats<<<512 / 64, 256, 0, stream>>>(h2, BATCH, 512, g2, b2, s2, t2);

    // 6) out = relu(bn2(h2)) @ W3^T   (BN+ReLU fused into A-load)
    gemm_nt<true><<<dim3(256 / 64, BATCH / 64), 256, 0, stream>>>(
        h2, 512, W3, 512, (float*)d_out, 256, BATCH, 256, 512, s2, t2);
}

// Round 2
// 664.715 us; speedup vs baseline: 2.1545x; 2.1545x over previous
//
#include <hip/hip_runtime.h>
#include <math.h>

#define SEQL 2048
#define BATCH 1024
#define CHUNK 256
#define NCH 8

// ---------------------------------------------------------------------------
// Generic NT GEMM: C[i][j] = sum_k opA(A[i][k]) * B[j][k]
// 64x64 tile, BK=32, 256 threads, 4x4 register blocking.
// FUSE: opA(a) = relu(sA[k]*a + tA[k])  (BN+ReLU fused on the K axis of A)
// ---------------------------------------------------------------------------
template<bool FUSE>
__global__ __launch_bounds__(256) void gemm_nt(
    const float* __restrict__ A, int lda,
    const float* __restrict__ B, int ldb,
    float* __restrict__ C, int ldc,
    int M, int N, int K,
    const float* __restrict__ sA, const float* __restrict__ tA)
{
    __shared__ float As[32][68];   // [k][m]
    __shared__ float Bs[32][68];   // [k][n]

    const int tid = threadIdx.x;
    const int tx = tid & 15;       // n-dir
    const int ty = tid >> 4;       // m-dir
    const int n0 = blockIdx.x * 64;
    const int m0 = blockIdx.y * 64;

    const int kk0 = tid & 31;
    const int rr0 = tid >> 5;

    float acc[4][4] = {};

    const int ktiles = (K + 31) >> 5;
    for (int kt = 0; kt < ktiles; ++kt) {
        const int kg = kt * 32 + kk0;
        const bool kin = (kg < K);
        float sv = 0.f, tv = 0.f;
        if (FUSE && kin) { sv = sA[kg]; tv = tA[kg]; }
        #pragma unroll
        for (int r = 0; r < 8; ++r) {
            const int m = rr0 + r * 8;
            float a = 0.f, b = 0.f;
            if (kin) {
                a = A[(size_t)(m0 + m) * lda + kg];
                if (FUSE) a = fmaxf(sv * a + tv, 0.f);
                b = B[(size_t)(n0 + m) * ldb + kg];
            }
            As[kk0][m] = a;
            Bs[kk0][m] = b;
        }
        __syncthreads();
        #pragma unroll
        for (int kk = 0; kk < 32; ++kk) {
            const float4 a4 = *reinterpret_cast<const float4*>(&As[kk][ty * 4]);
            const float4 b4 = *reinterpret_cast<const float4*>(&Bs[kk][tx * 4]);
            const float av[4] = {a4.x, a4.y, a4.z, a4.w};
            const float bv[4] = {b4.x, b4.y, b4.z, b4.w};
            #pragma unroll
            for (int i = 0; i < 4; ++i)
                #pragma unroll
                for (int j = 0; j < 4; ++j)
                    acc[i][j] += av[i] * bv[j];
        }
        __syncthreads();
    }

    #pragma unroll
    for (int i = 0; i < 4; ++i) {
        float4 o;
        o.x = acc[i][0]; o.y = acc[i][1]; o.z = acc[i][2]; o.w = acc[i][3];
        *reinterpret_cast<float4*>(&C[(size_t)(m0 + ty * 4 + i) * ldc + n0 + tx * 4]) = o;
    }
}

// ---------------------------------------------------------------------------
// Column-wise batchnorm stats: bn(x) = s[c]*x + t[c].
// ---------------------------------------------------------------------------
__global__ __launch_bounds__(256) void bn_stats(
    const float* __restrict__ X, int rows, int ld,
    const float* __restrict__ g, const float* __restrict__ b,
    float* __restrict__ s, float* __restrict__ t)
{
    __shared__ float rsum[4][64];
    __shared__ float rsq[4][64];
    const int tid = threadIdx.x;
    const int c = tid & 63;
    const int rg = tid >> 6;
    const int col = blockIdx.x * 64 + c;

    float sum = 0.f, sq = 0.f;
    for (int r = rg; r < rows; r += 4) {
        const float v = X[(size_t)r * ld + col];
        sum += v;
        sq += v * v;
    }
    rsum[rg][c] = sum;
    rsq[rg][c] = sq;
    __syncthreads();
    if (rg == 0) {
        sum = rsum[0][c] + rsum[1][c] + rsum[2][c] + rsum[3][c];
        sq  = rsq[0][c]  + rsq[1][c]  + rsq[2][c]  + rsq[3][c];
        const float inv = 1.0f / (float)rows;
        const float mean = sum * inv;
        const float var = fmaxf(sq * inv - mean * mean, 0.f);
        const float rstd = 1.0f / sqrtf(var + 1e-5f);
        const float sv = g[col] * rstd;
        s[col] = sv;
        t[col] = b[col] - mean * sv;
    }
}

// ---------------------------------------------------------------------------
// Chunked-parallel mamba scan. One block per batch row, 256 threads.
//  A': all threads compute per-step scalars (dt0,dt1,xs0,xs1) in parallel.
//  A'': 8 half-waves run 256-step local scans (h_in=0) -> (P, S) per chunk.
//  B : serial combine over 8 chunks -> H_in per chunk (h is linear in h_in).
//  C : re-run local scan seeded with H_in, emit y (in place over Y).
// ---------------------------------------------------------------------------
__global__ __launch_bounds__(256) void mamba_scan2(
    float* __restrict__ Y,
    const float* __restrict__ s1, const float* __restrict__ t1,
    const float* __restrict__ Win, const float* __restrict__ convw,
    const float* __restrict__ convb, const float* __restrict__ Wx,
    const float* __restrict__ Wdt, const float* __restrict__ bdt,
    const float* __restrict__ Alog, const float* __restrict__ Dp,
    const float* __restrict__ Wout)
{
    __shared__ __align__(16) float u_sh[SEQL];       // 8 KB
    __shared__ float dtx[SEQL][2];                   // 16 KB
    __shared__ float xsx[SEQL][2];                   // 16 KB
    __shared__ float Ps[NCH][32];
    __shared__ float Ss[NCH][32];
    __shared__ float Hin[NCH][32];

    const int tid = threadIdx.x;
    const int row = blockIdx.x;
    float* yrow = Y + (size_t)row * SEQL;

    // ---- stage u = bn1(C1 row) -------------------------------------------
    for (int i = tid; i < SEQL / 4; i += 256) {
        const float4 yv = reinterpret_cast<const float4*>(yrow)[i];
        const float4 sv = reinterpret_cast<const float4*>(s1)[i];
        const float4 tv = reinterpret_cast<const float4*>(t1)[i];
        float4 uv;
        uv.x = fmaf(sv.x, yv.x, tv.x);
        uv.y = fmaf(sv.y, yv.y, tv.y);
        uv.z = fmaf(sv.z, yv.z, tv.z);
        uv.w = fmaf(sv.w, yv.w, tv.w);
        reinterpret_cast<float4*>(u_sh)[i] = uv;
    }
    __syncthreads();

    // ---- phase A': per-step scalars, fully parallel ----------------------
    {
        const float wi0 = Win[0], wi1 = Win[1];
        const float cw00 = convw[0], cw01 = convw[1], cw02 = convw[2], cw03 = convw[3];
        const float cw10 = convw[4], cw11 = convw[5], cw12 = convw[6], cw13 = convw[7];
        const float cb0 = convb[0], cb1 = convb[1];
        const float wx00 = Wx[0], wx01 = Wx[1];
        const float wdt0 = Wdt[0], wdt1 = Wdt[1];
        const float bdt0 = bdt[0], bdt1 = bdt[1];
        #pragma unroll
        for (int j = 0; j < NCH; ++j) {
            const int l = tid + j * 256;
            const float u0  = u_sh[l];
            const float um1 = (l >= 1) ? u_sh[l - 1] : 0.f;
            const float um2 = (l >= 2) ? u_sh[l - 2] : 0.f;
            const float um3 = (l >= 3) ? u_sh[l - 3] : 0.f;
            const float c0 = fmaf(wi0, cw00 * um3 + cw01 * um2 + cw02 * um1 + cw03 * u0, cb0);
            const float c1 = fmaf(wi1, cw10 * um3 + cw11 * um2 + cw12 * um1 + cw13 * u0, cb1);
            const float xs0 = c0 / (1.f + __expf(-c0));
            const float xs1 = c1 / (1.f + __expf(-c1));
            const float d0 = xs0 * wx00 + xs1 * wx01;
            const float dt0 = __logf(1.f + __expf(fmaf(d0, wdt0, bdt0)));
            const float dt1 = __logf(1.f + __expf(fmaf(d0, wdt1, bdt1)));
            dtx[l][0] = dt0; dtx[l][1] = dt1;
            xsx[l][0] = xs0; xsx[l][1] = xs1;
        }
    }
    __syncthreads();

    // ---- lane decomposition ----------------------------------------------
    const int c  = tid >> 5;      // chunk = half-wave id
    const int l5 = tid & 31;
    const int e  = l5 >> 4;
    const int n  = l5 & 15;
    const int base = c * CHUNK;

    const float Aen  = -__expf(Alog[e * 16 + n]);
    const float wxB0 = Wx[(1 + n) * 2 + 0],  wxB1 = Wx[(1 + n) * 2 + 1];
    const float wxC0 = Wx[(17 + n) * 2 + 0], wxC1 = Wx[(17 + n) * 2 + 1];

    // ---- phase A'': local scan, h_in = 0 ---------------------------------
    {
        float h = 0.f, p = 1.f;
        #pragma unroll 4
        for (int i = 0; i < CHUNK; ++i) {
            const int l = base + i;
            const float dte = dtx[l][e];
            const float x0 = xsx[l][0], x1 = xsx[l][1];
            const float Bn = fmaf(x0, wxB0, x1 * wxB1);
            const float xe = e ? x1 : x0;
            const float dA = __expf(dte * Aen);
            h = fmaf(h, dA, dte * xe * Bn);
            p *= dA;
        }
        Ps[c][l5] = p;
        Ss[c][l5] = h;
    }
    __syncthreads();

    // ---- phase B: serial chunk combine -----------------------------------
    if (tid < 32) {
        float H = 0.f;
        #pragma unroll
        for (int cc = 0; cc < NCH; ++cc) {
            Hin[cc][tid] = H;
            H = fmaf(Ps[cc][tid], H, Ss[cc][tid]);
        }
    }
    __syncthreads();

    // ---- phase C: seeded re-scan + output --------------------------------
    {
        const float De = Dp[e], woute = Wout[e];
        const float wz = Win[2 + e];
        float h = Hin[c][l5];
        #pragma unroll 4
        for (int i = 0; i < CHUNK; ++i) {
            const int l = base + i;
            const float dte = dtx[l][e];
            const float x0 = xsx[l][0], x1 = xsx[l][1];
            const float Bn = fmaf(x0, wxB0, x1 * wxB1);
            const float Cn = fmaf(x0, wxC0, x1 * wxC1);
            const float xe = e ? x1 : x0;
            const float dA = __expf(dte * Aen);
            h = fmaf(h, dA, dte * xe * Bn);
            float py = h * Cn;
            py += __shfl_xor(py, 1);
            py += __shfl_xor(py, 2);
            py += __shfl_xor(py, 4);
            py += __shfl_xor(py, 8);
            const float ye = fmaf(De, xe, py);
            const float uu = u_sh[l];
            const float z = uu * wz;
            const float sz = (z / (1.f + __expf(-z))) * woute;
            float tt = ye * sz;
            tt += __shfl_xor(tt, 16);
            if (l5 == 0) yrow[l] = tt;
        }
    }
}

// ---------------------------------------------------------------------------
extern "C" void kernel_launch(void* const* d_in, const int* in_sizes, int n_in,
                              void* d_out, int out_size, void* d_ws, size_t ws_size,
                              hipStream_t stream)
{
    const float* x     = (const float*)d_in[0];
    const float* W1    = (const float*)d_in[1];
    const float* g1    = (const float*)d_in[2];
    const float* b1    = (const float*)d_in[3];
    const float* Win   = (const float*)d_in[4];
    const float* convw = (const float*)d_in[5];
    const float* convb = (const float*)d_in[6];
    const float* Wx    = (const float*)d_in[7];
    const float* Wdt   = (const float*)d_in[8];
    const float* bdt   = (const float*)d_in[9];
    const float* Alog  = (const float*)d_in[10];
    const float* Dp    = (const float*)d_in[11];
    const float* Wout  = (const float*)d_in[12];
    const float* W2    = (const float*)d_in[13];
    const float* g2    = (const float*)d_in[14];
    const float* b2    = (const float*)d_in[15];
    const float* W3    = (const float*)d_in[16];

    float* C1 = (float*)d_ws;                  // [1024][2048] -> mamba out
    float* h2 = C1 + (size_t)BATCH * SEQL;     // [1024][512]
    float* s1 = h2 + (size_t)BATCH * 512;      // [2048]
    float* t1 = s1 + SEQL;
    float* s2 = t1 + SEQL;                     // [512]
    float* t2 = s2 + 512;

    // 1) C1 = x @ W1^T
    gemm_nt<false><<<dim3(SEQL / 64, BATCH / 64), 256, 0, stream>>>(
        x, 1775, W1, 1775, C1, SEQL, BATCH, SEQL, 1775, nullptr, nullptr);

    // 2) BN1 stats
    bn_stats<<<SEQL / 64, 256, 0, stream>>>(C1, BATCH, SEQL, g1, b1, s1, t1);

    // 3) chunked-parallel mamba scan (in place over C1)
    mamba_scan2<<<BATCH, 256, 0, stream>>>(C1, s1, t1, Win, convw, convb,
                                           Wx, Wdt, bdt, Alog, Dp, Wout);

    // 4) h2 = mamba_out @ W2^T
    gemm_nt<false><<<dim3(512 / 64, BATCH / 64), 256, 0, stream>>>(
        C1, SEQL, W2, SEQL, h2, 512, BATCH, 512, SEQL, nullptr, nullptr);

    // 5) BN2 stats
    bn_stats<<<512 / 64, 256, 0, stream>>>(h2, BATCH, 512, g2, b2, s2, t2);

    // 6) out = relu(bn2(h2)) @ W3^T
    gemm_nt<true><<<dim3(256 / 64, BATCH / 64), 256, 0, stream>>>(
        h2, 512, W3, 512, (float*)d_out, 256, BATCH, 256, 512, s2, t2);
}

// Round 3
// 420.281 us; speedup vs baseline: 3.4076x; 1.5816x over previous
//
#include <hip/hip_runtime.h>
#include <math.h>

#define SEQL 2048
#define BATCH 1024
#define CHUNK 256
#define NCH 8

typedef short bf16x8 __attribute__((ext_vector_type(8)));
typedef float f32x4 __attribute__((ext_vector_type(4)));

// ---------------------------------------------------------------------------
// bf16 split helpers (RNE)
// ---------------------------------------------------------------------------
__device__ inline unsigned short f2bf(float f) {
    unsigned u = __float_as_uint(f);
    u += 0x7fffu + ((u >> 16) & 1u);
    return (unsigned short)(u >> 16);
}
__device__ inline float bf2f(unsigned short h) {
    return __uint_as_float((unsigned)h << 16);
}

__device__ inline void gl2lds16(const void* g, void* l) {
    __builtin_amdgcn_global_load_lds(
        (const __attribute__((address_space(1))) unsigned int*)g,
        (__attribute__((address_space(3))) unsigned int*)l, 16, 0, 0);
}

// ---------------------------------------------------------------------------
// Split-convert: src fp32 [R][K] -> hi/lo bf16 [R][Kp] (zero-padded K..Kp)
// ---------------------------------------------------------------------------
__global__ __launch_bounds__(256) void split_cvt(
    const float* __restrict__ src, int K, int Kp,
    unsigned short* __restrict__ hi, unsigned short* __restrict__ lo)
{
    const int r = blockIdx.x;
    const float* s = src + (size_t)r * K;
    unsigned short* ph = hi + (size_t)r * Kp;
    unsigned short* pl = lo + (size_t)r * Kp;
    for (int k = threadIdx.x; k < Kp; k += 256) {
        const float v = (k < K) ? s[k] : 0.f;
        const unsigned short h = f2bf(v);
        const unsigned short l = f2bf(v - bf2f(h));
        ph[k] = h; pl[k] = l;
    }
}

// Variant: v = relu(s[k]*(P0+P1)+t[k]) -> hi/lo (K == Kp)
__global__ __launch_bounds__(256) void split_cvt_bnrelu(
    const float* __restrict__ P0, const float* __restrict__ P1, int K,
    const float* __restrict__ sc, const float* __restrict__ tc,
    unsigned short* __restrict__ hi, unsigned short* __restrict__ lo)
{
    const int r = blockIdx.x;
    const float* p0 = P0 + (size_t)r * K;
    const float* p1 = P1 + (size_t)r * K;
    unsigned short* ph = hi + (size_t)r * K;
    unsigned short* pl = lo + (size_t)r * K;
    for (int k = threadIdx.x; k < K; k += 256) {
        const float v = fmaxf(fmaf(sc[k], p0[k] + p1[k], tc[k]), 0.f);
        const unsigned short h = f2bf(v);
        const unsigned short l = f2bf(v - bf2f(h));
        ph[k] = h; pl[k] = l;
    }
}

// ---------------------------------------------------------------------------
// Split-bf16 MFMA GEMM (NT): C[m][n] = sum_k A[m][k]*B[n][k], fp32-accurate
// via 3 products (hi*hi + lo*hi + hi*lo). 64x64 tile, BK=32, 4 waves,
// 16x16x32 MFMA, global_load_lds staging, m97 2-barrier structure.
// Optional split-K over blockIdx.z: chunk kb = z*ksteps, C += z*coff.
// ---------------------------------------------------------------------------
__global__ __launch_bounds__(256) void gemm_split(
    const unsigned short* __restrict__ Ahi, const unsigned short* __restrict__ Alo,
    const unsigned short* __restrict__ Bhi, const unsigned short* __restrict__ Blo,
    float* __restrict__ C, int ldc, int Kp, int ksteps, size_t coff)
{
    __shared__ __attribute__((aligned(16))) unsigned short sA[2][64 * 32];
    __shared__ __attribute__((aligned(16))) unsigned short sB[2][64 * 32];

    const int tid = threadIdx.x;
    const int wave = tid >> 6;
    const int lane = tid & 63;
    const int m0 = blockIdx.y * 64;
    const int n0 = blockIdx.x * 64;
    const int kb = blockIdx.z * ksteps;
    C += (size_t)blockIdx.z * coff;

    // staging: thread t covers row (t>>2), k-slot (t&3) (8 bf16 = 16B)
    const int sr = tid >> 2, ss = tid & 3;
    const size_t gk0 = (size_t)kb * 32 + ss * 8;
    const unsigned short* gAhi = Ahi + (size_t)(m0 + sr) * Kp + gk0;
    const unsigned short* gAlo = Alo + (size_t)(m0 + sr) * Kp + gk0;
    const unsigned short* gBhi = Bhi + (size_t)(n0 + sr) * Kp + gk0;
    const unsigned short* gBlo = Blo + (size_t)(n0 + sr) * Kp + gk0;
    const int wbase = wave * 512;     // 64 lanes * 16B = 512 shorts per wave

    // fragment geometry
    const int wr = wave >> 1, wc = wave & 1;
    const int li = lane & 15, gq = lane >> 4;

    f32x4 acc[2][2];
    #pragma unroll
    for (int i = 0; i < 2; ++i)
        #pragma unroll
        for (int j = 0; j < 2; ++j)
            #pragma unroll
            for (int v = 0; v < 4; ++v) acc[i][j][v] = 0.f;

    for (int kt = 0; kt < ksteps; ++kt) {
        const size_t go = (size_t)kt * 32;
        gl2lds16(gAhi + go, &sA[0][wbase]);
        gl2lds16(gAlo + go, &sA[1][wbase]);
        gl2lds16(gBhi + go, &sB[0][wbase]);
        gl2lds16(gBlo + go, &sB[1][wbase]);
        __syncthreads();

        bf16x8 ah[2], al[2], bh[2], bl[2];
        #pragma unroll
        for (int mi = 0; mi < 2; ++mi) {
            const int idx = (wr * 32 + mi * 16 + li) * 32 + gq * 8;
            ah[mi] = *(const bf16x8*)&sA[0][idx];
            al[mi] = *(const bf16x8*)&sA[1][idx];
        }
        #pragma unroll
        for (int ni = 0; ni < 2; ++ni) {
            const int idx = (wc * 32 + ni * 16 + li) * 32 + gq * 8;
            bh[ni] = *(const bf16x8*)&sB[0][idx];
            bl[ni] = *(const bf16x8*)&sB[1][idx];
        }
        #pragma unroll
        for (int mi = 0; mi < 2; ++mi)
            #pragma unroll
            for (int ni = 0; ni < 2; ++ni) {
                acc[mi][ni] = __builtin_amdgcn_mfma_f32_16x16x32_bf16(ah[mi], bh[ni], acc[mi][ni], 0, 0, 0);
                acc[mi][ni] = __builtin_amdgcn_mfma_f32_16x16x32_bf16(al[mi], bh[ni], acc[mi][ni], 0, 0, 0);
                acc[mi][ni] = __builtin_amdgcn_mfma_f32_16x16x32_bf16(ah[mi], bl[ni], acc[mi][ni], 0, 0, 0);
            }
        __syncthreads();
    }

    #pragma unroll
    for (int mi = 0; mi < 2; ++mi)
        #pragma unroll
        for (int ni = 0; ni < 2; ++ni) {
            const int col = n0 + wc * 32 + ni * 16 + li;
            #pragma unroll
            for (int i = 0; i < 4; ++i) {
                const int row = m0 + wr * 32 + mi * 16 + gq * 4 + i;
                C[(size_t)row * ldc + col] = acc[mi][ni][i];
            }
        }
}

// ---------------------------------------------------------------------------
// Column-wise batchnorm stats: bn(x) = s[c]*x + t[c]. Optional X2 (sum).
// ---------------------------------------------------------------------------
__global__ __launch_bounds__(256) void bn_stats(
    const float* __restrict__ X, const float* __restrict__ X2, int rows, int ld,
    const float* __restrict__ g, const float* __restrict__ b,
    float* __restrict__ s, float* __restrict__ t)
{
    __shared__ float rsum[4][64];
    __shared__ float rsq[4][64];
    const int tid = threadIdx.x;
    const int c = tid & 63;
    const int rg = tid >> 6;
    const int col = blockIdx.x * 64 + c;

    float sum = 0.f, sq = 0.f;
    for (int r = rg; r < rows; r += 4) {
        float v = X[(size_t)r * ld + col];
        if (X2) v += X2[(size_t)r * ld + col];
        sum += v;
        sq += v * v;
    }
    rsum[rg][c] = sum;
    rsq[rg][c] = sq;
    __syncthreads();
    if (rg == 0) {
        sum = rsum[0][c] + rsum[1][c] + rsum[2][c] + rsum[3][c];
        sq  = rsq[0][c]  + rsq[1][c]  + rsq[2][c]  + rsq[3][c];
        const float inv = 1.0f / (float)rows;
        const float mean = sum * inv;
        const float var = fmaxf(sq * inv - mean * mean, 0.f);
        const float rstd = 1.0f / sqrtf(var + 1e-5f);
        const float sv = g[col] * rstd;
        s[col] = sv;
        t[col] = b[col] - mean * sv;
    }
}

// ---------------------------------------------------------------------------
// Chunked-parallel mamba scan (unchanged from round 2).
// ---------------------------------------------------------------------------
__global__ __launch_bounds__(256) void mamba_scan2(
    float* __restrict__ Y,
    const float* __restrict__ s1, const float* __restrict__ t1,
    const float* __restrict__ Win, const float* __restrict__ convw,
    const float* __restrict__ convb, const float* __restrict__ Wx,
    const float* __restrict__ Wdt, const float* __restrict__ bdt,
    const float* __restrict__ Alog, const float* __restrict__ Dp,
    const float* __restrict__ Wout)
{
    __shared__ __align__(16) float u_sh[SEQL];
    __shared__ float dtx[SEQL][2];
    __shared__ float xsx[SEQL][2];
    __shared__ float Ps[NCH][32];
    __shared__ float Ss[NCH][32];
    __shared__ float Hin[NCH][32];

    const int tid = threadIdx.x;
    const int row = blockIdx.x;
    float* yrow = Y + (size_t)row * SEQL;

    for (int i = tid; i < SEQL / 4; i += 256) {
        const float4 yv = reinterpret_cast<const float4*>(yrow)[i];
        const float4 sv = reinterpret_cast<const float4*>(s1)[i];
        const float4 tv = reinterpret_cast<const float4*>(t1)[i];
        float4 uv;
        uv.x = fmaf(sv.x, yv.x, tv.x);
        uv.y = fmaf(sv.y, yv.y, tv.y);
        uv.z = fmaf(sv.z, yv.z, tv.z);
        uv.w = fmaf(sv.w, yv.w, tv.w);
        reinterpret_cast<float4*>(u_sh)[i] = uv;
    }
    __syncthreads();

    {
        const float wi0 = Win[0], wi1 = Win[1];
        const float cw00 = convw[0], cw01 = convw[1], cw02 = convw[2], cw03 = convw[3];
        const float cw10 = convw[4], cw11 = convw[5], cw12 = convw[6], cw13 = convw[7];
        const float cb0 = convb[0], cb1 = convb[1];
        const float wx00 = Wx[0], wx01 = Wx[1];
        const float wdt0 = Wdt[0], wdt1 = Wdt[1];
        const float bdt0 = bdt[0], bdt1 = bdt[1];
        #pragma unroll
        for (int j = 0; j < NCH; ++j) {
            const int l = tid + j * 256;
            const float u0  = u_sh[l];
            const float um1 = (l >= 1) ? u_sh[l - 1] : 0.f;
            const float um2 = (l >= 2) ? u_sh[l - 2] : 0.f;
            const float um3 = (l >= 3) ? u_sh[l - 3] : 0.f;
            const float c0 = fmaf(wi0, cw00 * um3 + cw01 * um2 + cw02 * um1 + cw03 * u0, cb0);
            const float c1 = fmaf(wi1, cw10 * um3 + cw11 * um2 + cw12 * um1 + cw13 * u0, cb1);
            const float xs0 = c0 / (1.f + __expf(-c0));
            const float xs1 = c1 / (1.f + __expf(-c1));
            const float d0 = xs0 * wx00 + xs1 * wx01;
            const float dt0 = __logf(1.f + __expf(fmaf(d0, wdt0, bdt0)));
            const float dt1 = __logf(1.f + __expf(fmaf(d0, wdt1, bdt1)));
            dtx[l][0] = dt0; dtx[l][1] = dt1;
            xsx[l][0] = xs0; xsx[l][1] = xs1;
        }
    }
    __syncthreads();

    const int c  = tid >> 5;
    const int l5 = tid & 31;
    const int e  = l5 >> 4;
    const int n  = l5 & 15;
    const int base = c * CHUNK;

    const float Aen  = -__expf(Alog[e * 16 + n]);
    const float wxB0 = Wx[(1 + n) * 2 + 0],  wxB1 = Wx[(1 + n) * 2 + 1];
    const float wxC0 = Wx[(17 + n) * 2 + 0], wxC1 = Wx[(17 + n) * 2 + 1];

    {
        float h = 0.f, p = 1.f;
        #pragma unroll 4
        for (int i = 0; i < CHUNK; ++i) {
            const int l = base + i;
            const float dte = dtx[l][e];
            const float x0 = xsx[l][0], x1 = xsx[l][1];
            const float Bn = fmaf(x0, wxB0, x1 * wxB1);
            const float xe = e ? x1 : x0;
            const float dA = __expf(dte * Aen);
            h = fmaf(h, dA, dte * xe * Bn);
            p *= dA;
        }
        Ps[c][l5] = p;
        Ss[c][l5] = h;
    }
    __syncthreads();

    if (tid < 32) {
        float H = 0.f;
        #pragma unroll
        for (int cc = 0; cc < NCH; ++cc) {
            Hin[cc][tid] = H;
            H = fmaf(Ps[cc][tid], H, Ss[cc][tid]);
        }
    }
    __syncthreads();

    {
        const float De = Dp[e], woute = Wout[e];
        const float wz = Win[2 + e];
        float h = Hin[c][l5];
        #pragma unroll 4
        for (int i = 0; i < CHUNK; ++i) {
            const int l = base + i;
            const float dte = dtx[l][e];
            const float x0 = xsx[l][0], x1 = xsx[l][1];
            const float Bn = fmaf(x0, wxB0, x1 * wxB1);
            const float Cn = fmaf(x0, wxC0, x1 * wxC1);
            const float xe = e ? x1 : x0;
            const float dA = __expf(dte * Aen);
            h = fmaf(h, dA, dte * xe * Bn);
            float py = h * Cn;
            py += __shfl_xor(py, 1);
            py += __shfl_xor(py, 2);
            py += __shfl_xor(py, 4);
            py += __shfl_xor(py, 8);
            const float ye = fmaf(De, xe, py);
            const float uu = u_sh[l];
            const float z = uu * wz;
            const float sz = (z / (1.f + __expf(-z))) * woute;
            float tt = ye * sz;
            tt += __shfl_xor(tt, 16);
            if (l5 == 0) yrow[l] = tt;
        }
    }
}

// ---------------------------------------------------------------------------
extern "C" void kernel_launch(void* const* d_in, const int* in_sizes, int n_in,
                              void* d_out, int out_size, void* d_ws, size_t ws_size,
                              hipStream_t stream)
{
    const float* x     = (const float*)d_in[0];
    const float* W1    = (const float*)d_in[1];
    const float* g1    = (const float*)d_in[2];
    const float* b1    = (const float*)d_in[3];
    const float* Win   = (const float*)d_in[4];
    const float* convw = (const float*)d_in[5];
    const float* convb = (const float*)d_in[6];
    const float* Wx    = (const float*)d_in[7];
    const float* Wdt   = (const float*)d_in[8];
    const float* bdt   = (const float*)d_in[9];
    const float* Alog  = (const float*)d_in[10];
    const float* Dp    = (const float*)d_in[11];
    const float* Wout  = (const float*)d_in[12];
    const float* W2    = (const float*)d_in[13];
    const float* g2    = (const float*)d_in[14];
    const float* b2    = (const float*)d_in[15];
    const float* W3    = (const float*)d_in[16];

    unsigned char* base = (unsigned char*)d_ws;
    float* C1 = (float*)(base + 0);                        // 8,388,608 B
    float* P0 = (float*)(base + 8388608);                  // 2,097,152
    float* P1 = (float*)(base + 10485760);                 // 2,097,152
    float* s1 = (float*)(base + 12582912);                 // 8 KB
    float* t1 = (float*)(base + 12591104);
    float* s2 = (float*)(base + 12599296);                 // 2 KB
    float* t2 = (float*)(base + 12601344);
    // pool X: xhi/xlo, then a2hi/a2lo (8,388,608 B total)
    unsigned char* pX = base + 12603392;
    unsigned short* xhi  = (unsigned short*)(pX);
    unsigned short* xlo  = (unsigned short*)(pX + 4194304);
    unsigned short* a2hi = (unsigned short*)(pX);
    unsigned short* a2lo = (unsigned short*)(pX + 4194304);
    // pool W: w1hi/lo, then {w2hi/lo, h3hi/lo, w3hi/lo} (14,680,064 B total)
    unsigned char* pW = base + 20992000;
    unsigned short* w1hi = (unsigned short*)(pW);
    unsigned short* w1lo = (unsigned short*)(pW + 7340032);
    unsigned short* w2hi = (unsigned short*)(pW);
    unsigned short* w2lo = (unsigned short*)(pW + 2097152);
    unsigned short* h3hi = (unsigned short*)(pW + 4194304);
    unsigned short* h3lo = (unsigned short*)(pW + 5242880);
    unsigned short* w3hi = (unsigned short*)(pW + 6291456);
    unsigned short* w3lo = (unsigned short*)(pW + 6553600);

    // 1) split x, W1 ; GEMM1: C1 = x @ W1^T   (M=1024,N=2048,K=1775,Kp=1792)
    split_cvt<<<1024, 256, 0, stream>>>(x, 1775, 1792, xhi, xlo);
    split_cvt<<<2048, 256, 0, stream>>>(W1, 1775, 1792, w1hi, w1lo);
    gemm_split<<<dim3(32, 16, 1), 256, 0, stream>>>(
        xhi, xlo, w1hi, w1lo, C1, 2048, 1792, 56, 0);

    // 2) BN1 stats
    bn_stats<<<32, 256, 0, stream>>>(C1, nullptr, 1024, 2048, g1, b1, s1, t1);

    // 3) mamba scan (in place over C1)
    mamba_scan2<<<1024, 256, 0, stream>>>(C1, s1, t1, Win, convw, convb,
                                          Wx, Wdt, bdt, Alog, Dp, Wout);

    // 4) split C1, W2 ; GEMM2 (split-K=2): P0/P1 partials  (1024x512xK=2048)
    split_cvt<<<1024, 256, 0, stream>>>(C1, 2048, 2048, a2hi, a2lo);
    split_cvt<<<512, 256, 0, stream>>>(W2, 2048, 2048, w2hi, w2lo);
    gemm_split<<<dim3(8, 16, 2), 256, 0, stream>>>(
        a2hi, a2lo, w2hi, w2lo, P0, 512, 2048, 32, (size_t)1024 * 512);

    // 5) BN2 stats over P0+P1
    bn_stats<<<8, 256, 0, stream>>>(P0, P1, 1024, 512, g2, b2, s2, t2);

    // 6) h3 = relu(bn2(P0+P1)) split ; W3 split ; GEMM3 -> d_out (1024x256x512)
    split_cvt_bnrelu<<<1024, 256, 0, stream>>>(P0, P1, 512, s2, t2, h3hi, h3lo);
    split_cvt<<<256, 256, 0, stream>>>(W3, 512, 512, w3hi, w3lo);
    gemm_split<<<dim3(4, 16, 1), 256, 0, stream>>>(
        h3hi, h3lo, w3hi, w3lo, (float*)d_out, 256, 512, 16, 0);
}

// Round 4
// 375.374 us; speedup vs baseline: 3.8153x; 1.1196x over previous
//
#include <hip/hip_runtime.h>
#include <math.h>

#define SEQL 2048
#define BATCH 1024
#define CHUNK 256
#define NCH 8

typedef short bf16x8 __attribute__((ext_vector_type(8)));
typedef float f32x4 __attribute__((ext_vector_type(4)));

// ---------------------------------------------------------------------------
// bf16 split helpers (RNE)
// ---------------------------------------------------------------------------
__device__ inline unsigned short f2bf(float f) {
    unsigned u = __float_as_uint(f);
    u += 0x7fffu + ((u >> 16) & 1u);
    return (unsigned short)(u >> 16);
}
__device__ inline float bf2f(unsigned short h) {
    return __uint_as_float((unsigned)h << 16);
}

__device__ inline void gl2lds16(const void* g, void* l) {
    __builtin_amdgcn_global_load_lds(
        (const __attribute__((address_space(1))) unsigned int*)g,
        (__attribute__((address_space(3))) unsigned int*)l, 16, 0, 0);
}

// ---------------------------------------------------------------------------
// Split-convert: src fp32 [R][K] -> hi/lo bf16 [R][Kp] (zero-padded K..Kp)
// ---------------------------------------------------------------------------
__global__ __launch_bounds__(256) void split_cvt(
    const float* __restrict__ src, int K, int Kp,
    unsigned short* __restrict__ hi, unsigned short* __restrict__ lo)
{
    const int r = blockIdx.x;
    const float* s = src + (size_t)r * K;
    unsigned short* ph = hi + (size_t)r * Kp;
    unsigned short* pl = lo + (size_t)r * Kp;
    for (int k = threadIdx.x; k < Kp; k += 256) {
        const float v = (k < K) ? s[k] : 0.f;
        const unsigned short h = f2bf(v);
        const unsigned short l = f2bf(v - bf2f(h));
        ph[k] = h; pl[k] = l;
    }
}

// Variant: v = relu(s[k]*(P0+P1)+t[k]) -> hi/lo (K == Kp)
__global__ __launch_bounds__(256) void split_cvt_bnrelu(
    const float* __restrict__ P0, const float* __restrict__ P1, int K,
    const float* __restrict__ sc, const float* __restrict__ tc,
    unsigned short* __restrict__ hi, unsigned short* __restrict__ lo)
{
    const int r = blockIdx.x;
    const float* p0 = P0 + (size_t)r * K;
    const float* p1 = P1 + (size_t)r * K;
    unsigned short* ph = hi + (size_t)r * K;
    unsigned short* pl = lo + (size_t)r * K;
    for (int k = threadIdx.x; k < K; k += 256) {
        const float v = fmaxf(fmaf(sc[k], p0[k] + p1[k], tc[k]), 0.f);
        const unsigned short h = f2bf(v);
        const unsigned short l = f2bf(v - bf2f(h));
        ph[k] = h; pl[k] = l;
    }
}

// ---------------------------------------------------------------------------
// Split-bf16 MFMA GEMM (NT): C = A @ B^T, fp32-grade via hi*hi+lo*hi+hi*lo.
// 64x64 tile, BK=32, 4 waves, 16x16x32 MFMA, global_load_lds staging.
// ---------------------------------------------------------------------------
__global__ __launch_bounds__(256) void gemm_split(
    const unsigned short* __restrict__ Ahi, const unsigned short* __restrict__ Alo,
    const unsigned short* __restrict__ Bhi, const unsigned short* __restrict__ Blo,
    float* __restrict__ C, int ldc, int Kp, int ksteps, size_t coff)
{
    __shared__ __attribute__((aligned(16))) unsigned short sA[2][64 * 32];
    __shared__ __attribute__((aligned(16))) unsigned short sB[2][64 * 32];

    const int tid = threadIdx.x;
    const int wave = tid >> 6;
    const int lane = tid & 63;
    const int m0 = blockIdx.y * 64;
    const int n0 = blockIdx.x * 64;
    const int kb = blockIdx.z * ksteps;
    C += (size_t)blockIdx.z * coff;

    const int sr = tid >> 2, ss = tid & 3;
    const size_t gk0 = (size_t)kb * 32 + ss * 8;
    const unsigned short* gAhi = Ahi + (size_t)(m0 + sr) * Kp + gk0;
    const unsigned short* gAlo = Alo + (size_t)(m0 + sr) * Kp + gk0;
    const unsigned short* gBhi = Bhi + (size_t)(n0 + sr) * Kp + gk0;
    const unsigned short* gBlo = Blo + (size_t)(n0 + sr) * Kp + gk0;
    const int wbase = wave * 512;

    const int wr = wave >> 1, wc = wave & 1;
    const int li = lane & 15, gq = lane >> 4;

    f32x4 acc[2][2];
    #pragma unroll
    for (int i = 0; i < 2; ++i)
        #pragma unroll
        for (int j = 0; j < 2; ++j)
            #pragma unroll
            for (int v = 0; v < 4; ++v) acc[i][j][v] = 0.f;

    for (int kt = 0; kt < ksteps; ++kt) {
        const size_t go = (size_t)kt * 32;
        gl2lds16(gAhi + go, &sA[0][wbase]);
        gl2lds16(gAlo + go, &sA[1][wbase]);
        gl2lds16(gBhi + go, &sB[0][wbase]);
        gl2lds16(gBlo + go, &sB[1][wbase]);
        __syncthreads();

        bf16x8 ah[2], al[2], bh[2], bl[2];
        #pragma unroll
        for (int mi = 0; mi < 2; ++mi) {
            const int idx = (wr * 32 + mi * 16 + li) * 32 + gq * 8;
            ah[mi] = *(const bf16x8*)&sA[0][idx];
            al[mi] = *(const bf16x8*)&sA[1][idx];
        }
        #pragma unroll
        for (int ni = 0; ni < 2; ++ni) {
            const int idx = (wc * 32 + ni * 16 + li) * 32 + gq * 8;
            bh[ni] = *(const bf16x8*)&sB[0][idx];
            bl[ni] = *(const bf16x8*)&sB[1][idx];
        }
        #pragma unroll
        for (int mi = 0; mi < 2; ++mi)
            #pragma unroll
            for (int ni = 0; ni < 2; ++ni) {
                acc[mi][ni] = __builtin_amdgcn_mfma_f32_16x16x32_bf16(ah[mi], bh[ni], acc[mi][ni], 0, 0, 0);
                acc[mi][ni] = __builtin_amdgcn_mfma_f32_16x16x32_bf16(al[mi], bh[ni], acc[mi][ni], 0, 0, 0);
                acc[mi][ni] = __builtin_amdgcn_mfma_f32_16x16x32_bf16(ah[mi], bl[ni], acc[mi][ni], 0, 0, 0);
            }
        __syncthreads();
    }

    #pragma unroll
    for (int mi = 0; mi < 2; ++mi)
        #pragma unroll
        for (int ni = 0; ni < 2; ++ni) {
            const int col = n0 + wc * 32 + ni * 16 + li;
            #pragma unroll
            for (int i = 0; i < 4; ++i) {
                const int row = m0 + wr * 32 + mi * 16 + gq * 4 + i;
                C[(size_t)row * ldc + col] = acc[mi][ni][i];
            }
        }
}

// ---------------------------------------------------------------------------
// Column-wise batchnorm stats: bn(x) = s[c]*x + t[c]. Optional X2 (sum).
// ---------------------------------------------------------------------------
__global__ __launch_bounds__(256) void bn_stats(
    const float* __restrict__ X, const float* __restrict__ X2, int rows, int ld,
    const float* __restrict__ g, const float* __restrict__ b,
    float* __restrict__ s, float* __restrict__ t)
{
    __shared__ float rsum[4][64];
    __shared__ float rsq[4][64];
    const int tid = threadIdx.x;
    const int c = tid & 63;
    const int rg = tid >> 6;
    const int col = blockIdx.x * 64 + c;

    float sum = 0.f, sq = 0.f;
    for (int r = rg; r < rows; r += 4) {
        float v = X[(size_t)r * ld + col];
        if (X2) v += X2[(size_t)r * ld + col];
        sum += v;
        sq += v * v;
    }
    rsum[rg][c] = sum;
    rsq[rg][c] = sq;
    __syncthreads();
    if (rg == 0) {
        sum = rsum[0][c] + rsum[1][c] + rsum[2][c] + rsum[3][c];
        sq  = rsq[0][c]  + rsq[1][c]  + rsq[2][c]  + rsq[3][c];
        const float inv = 1.0f / (float)rows;
        const float mean = sum * inv;
        const float var = fmaxf(sq * inv - mean * mean, 0.f);
        const float rstd = 1.0f / sqrtf(var + 1e-5f);
        const float sv = g[col] * rstd;
        s[col] = sv;
        t[col] = b[col] - mean * sv;
    }
}

// ---------------------------------------------------------------------------
// Chunked-parallel mamba scan, v3.
//  - packed LDS float4 (dt0,dt1,x0,x1): one broadcast ds_read_b128 per step
//  - phase A' contiguous-per-thread, u kept in registers (shfl in phase C)
//  - 35 KB LDS -> 4 blocks/CU
// ---------------------------------------------------------------------------
__global__ __launch_bounds__(256, 4) void mamba_scan3(
    float* __restrict__ Y,
    const float* __restrict__ s1, const float* __restrict__ t1,
    const float* __restrict__ Win, const float* __restrict__ convw,
    const float* __restrict__ convb, const float* __restrict__ Wx,
    const float* __restrict__ Wdt, const float* __restrict__ bdt,
    const float* __restrict__ Alog, const float* __restrict__ Dp,
    const float* __restrict__ Wout)
{
    __shared__ __align__(16) float4 pk[SEQL];   // 32 KB (dt0,dt1,x0,x1)
    __shared__ float Ps[NCH][32];
    __shared__ float Ss[NCH][32];
    __shared__ float Hin[NCH][32];

    const int tid = threadIdx.x;
    const int row = blockIdx.x;
    float* yrow = Y + (size_t)row * SEQL;

    float u_sav[8];

    // ---- phase A': steps [8*tid, 8*tid+8), conv window in registers ------
    {
        const int l0 = tid * 8;
        float4 ym = {0.f,0.f,0.f,0.f}, sm = {0.f,0.f,0.f,0.f}, tm = {0.f,0.f,0.f,0.f};
        if (tid > 0) {
            ym = *reinterpret_cast<const float4*>(&yrow[l0 - 4]);
            sm = *reinterpret_cast<const float4*>(&s1[l0 - 4]);
            tm = *reinterpret_cast<const float4*>(&t1[l0 - 4]);
        }
        const float4 y0 = *reinterpret_cast<const float4*>(&yrow[l0]);
        const float4 s0 = *reinterpret_cast<const float4*>(&s1[l0]);
        const float4 t0 = *reinterpret_cast<const float4*>(&t1[l0]);
        const float4 y1 = *reinterpret_cast<const float4*>(&yrow[l0 + 4]);
        const float4 s4 = *reinterpret_cast<const float4*>(&s1[l0 + 4]);
        const float4 t4 = *reinterpret_cast<const float4*>(&t1[l0 + 4]);

        float ua[12];
        ua[0]  = fmaf(sm.x, ym.x, tm.x);
        ua[1]  = fmaf(sm.y, ym.y, tm.y);
        ua[2]  = fmaf(sm.z, ym.z, tm.z);
        ua[3]  = fmaf(sm.w, ym.w, tm.w);
        ua[4]  = fmaf(s0.x, y0.x, t0.x);
        ua[5]  = fmaf(s0.y, y0.y, t0.y);
        ua[6]  = fmaf(s0.z, y0.z, t0.z);
        ua[7]  = fmaf(s0.w, y0.w, t0.w);
        ua[8]  = fmaf(s4.x, y1.x, t4.x);
        ua[9]  = fmaf(s4.y, y1.y, t4.y);
        ua[10] = fmaf(s4.z, y1.z, t4.z);
        ua[11] = fmaf(s4.w, y1.w, t4.w);

        const float wi0 = Win[0], wi1 = Win[1];
        const float cw00 = convw[0], cw01 = convw[1], cw02 = convw[2], cw03 = convw[3];
        const float cw10 = convw[4], cw11 = convw[5], cw12 = convw[6], cw13 = convw[7];
        const float cb0 = convb[0], cb1 = convb[1];
        const float wx00 = Wx[0], wx01 = Wx[1];
        const float wdt0 = Wdt[0], wdt1 = Wdt[1];
        const float bdt0 = bdt[0], bdt1 = bdt[1];

        #pragma unroll
        for (int j = 0; j < 8; ++j) {
            const float u0 = ua[j + 4], um1 = ua[j + 3], um2 = ua[j + 2], um3 = ua[j + 1];
            const float c0 = fmaf(wi0, cw00 * um3 + cw01 * um2 + cw02 * um1 + cw03 * u0, cb0);
            const float c1 = fmaf(wi1, cw10 * um3 + cw11 * um2 + cw12 * um1 + cw13 * u0, cb1);
            const float xs0 = c0 / (1.f + __expf(-c0));
            const float xs1 = c1 / (1.f + __expf(-c1));
            const float d0 = xs0 * wx00 + xs1 * wx01;
            const float dt0 = __logf(1.f + __expf(fmaf(d0, wdt0, bdt0)));
            const float dt1 = __logf(1.f + __expf(fmaf(d0, wdt1, bdt1)));
            float4 rec; rec.x = dt0; rec.y = dt1; rec.z = xs0; rec.w = xs1;
            pk[l0 + j] = rec;
            u_sav[j] = u0;
        }
    }
    __syncthreads();

    // ---- lane decomposition ----------------------------------------------
    const int c  = tid >> 5;       // chunk = half-wave
    const int l5 = tid & 31;
    const int e  = l5 >> 4;
    const int n  = l5 & 15;
    const int base = c * CHUNK;

    const float Aen  = -__expf(Alog[e * 16 + n]);
    const float wxB0 = Wx[(1 + n) * 2 + 0],  wxB1 = Wx[(1 + n) * 2 + 1];
    const float wxC0 = Wx[(17 + n) * 2 + 0], wxC1 = Wx[(17 + n) * 2 + 1];

    // ---- phase A'': local scan, h_in = 0 ---------------------------------
    {
        float h = 0.f, p = 1.f;
        for (int i0 = 0; i0 < CHUNK; i0 += 8) {
            #pragma unroll
            for (int j = 0; j < 8; ++j) {
                const float4 v = pk[base + i0 + j];
                const float dte = e ? v.y : v.x;
                const float xe  = e ? v.w : v.z;
                const float Bn = fmaf(v.z, wxB0, v.w * wxB1);
                const float dA = __expf(dte * Aen);
                h = fmaf(h, dA, dte * xe * Bn);
                p *= dA;
            }
        }
        Ps[c][l5] = p;
        Ss[c][l5] = h;
    }
    __syncthreads();

    // ---- phase B: serial chunk combine -----------------------------------
    if (tid < 32) {
        float H = 0.f;
        #pragma unroll
        for (int cc = 0; cc < NCH; ++cc) {
            Hin[cc][tid] = H;
            H = fmaf(Ps[cc][tid], H, Ss[cc][tid]);
        }
    }
    __syncthreads();

    // ---- phase C: seeded re-scan + output --------------------------------
    {
        const float De = Dp[e], woute = Wout[e];
        const float wz = Win[2 + e];
        const int srcbase = tid & 32;
        float h = Hin[c][l5];
        for (int i0 = 0; i0 < CHUNK; i0 += 8) {
            #pragma unroll
            for (int j = 0; j < 8; ++j) {
                const int i = i0 + j;
                const float4 v = pk[base + i];
                const float dte = e ? v.y : v.x;
                const float xe  = e ? v.w : v.z;
                const float Bn = fmaf(v.z, wxB0, v.w * wxB1);
                const float Cn = fmaf(v.z, wxC0, v.w * wxC1);
                const float dA = __expf(dte * Aen);
                h = fmaf(h, dA, dte * xe * Bn);
                float py = h * Cn;
                py += __shfl_xor(py, 1);
                py += __shfl_xor(py, 2);
                py += __shfl_xor(py, 4);
                py += __shfl_xor(py, 8);
                const float ye = fmaf(De, xe, py);
                const float uu = __shfl(u_sav[j], srcbase + (i >> 3), 64);
                const float z = uu * wz;
                const float sz = (z / (1.f + __expf(-z))) * woute;
                float tt = ye * sz;
                tt += __shfl_xor(tt, 16);
                if (l5 == 0) yrow[base + i] = tt;
            }
        }
    }
}

// ---------------------------------------------------------------------------
extern "C" void kernel_launch(void* const* d_in, const int* in_sizes, int n_in,
                              void* d_out, int out_size, void* d_ws, size_t ws_size,
                              hipStream_t stream)
{
    const float* x     = (const float*)d_in[0];
    const float* W1    = (const float*)d_in[1];
    const float* g1    = (const float*)d_in[2];
    const float* b1    = (const float*)d_in[3];
    const float* Win   = (const float*)d_in[4];
    const float* convw = (const float*)d_in[5];
    const float* convb = (const float*)d_in[6];
    const float* Wx    = (const float*)d_in[7];
    const float* Wdt   = (const float*)d_in[8];
    const float* bdt   = (const float*)d_in[9];
    const float* Alog  = (const float*)d_in[10];
    const float* Dp    = (const float*)d_in[11];
    const float* Wout  = (const float*)d_in[12];
    const float* W2    = (const float*)d_in[13];
    const float* g2    = (const float*)d_in[14];
    const float* b2    = (const float*)d_in[15];
    const float* W3    = (const float*)d_in[16];

    unsigned char* base = (unsigned char*)d_ws;
    float* C1 = (float*)(base + 0);                        // 8,388,608 B
    float* P0 = (float*)(base + 8388608);                  // 2,097,152
    float* P1 = (float*)(base + 10485760);                 // 2,097,152
    float* s1 = (float*)(base + 12582912);
    float* t1 = (float*)(base + 12591104);
    float* s2 = (float*)(base + 12599296);
    float* t2 = (float*)(base + 12601344);
    unsigned char* pX = base + 12603392;
    unsigned short* xhi  = (unsigned short*)(pX);
    unsigned short* xlo  = (unsigned short*)(pX + 4194304);
    unsigned short* a2hi = (unsigned short*)(pX);
    unsigned short* a2lo = (unsigned short*)(pX + 4194304);
    unsigned char* pW = base + 20992000;
    unsigned short* w1hi = (unsigned short*)(pW);
    unsigned short* w1lo = (unsigned short*)(pW + 7340032);
    unsigned short* w2hi = (unsigned short*)(pW);
    unsigned short* w2lo = (unsigned short*)(pW + 2097152);
    unsigned short* h3hi = (unsigned short*)(pW + 4194304);
    unsigned short* h3lo = (unsigned short*)(pW + 5242880);
    unsigned short* w3hi = (unsigned short*)(pW + 6291456);
    unsigned short* w3lo = (unsigned short*)(pW + 6553600);

    // 1) split x, W1 ; GEMM1: C1 = x @ W1^T
    split_cvt<<<1024, 256, 0, stream>>>(x, 1775, 1792, xhi, xlo);
    split_cvt<<<2048, 256, 0, stream>>>(W1, 1775, 1792, w1hi, w1lo);
    gemm_split<<<dim3(32, 16, 1), 256, 0, stream>>>(
        xhi, xlo, w1hi, w1lo, C1, 2048, 1792, 56, 0);

    // 2) BN1 stats
    bn_stats<<<32, 256, 0, stream>>>(C1, nullptr, 1024, 2048, g1, b1, s1, t1);

    // 3) mamba scan (in place over C1)
    mamba_scan3<<<1024, 256, 0, stream>>>(C1, s1, t1, Win, convw, convb,
                                          Wx, Wdt, bdt, Alog, Dp, Wout);

    // 4) split C1, W2 ; GEMM2 (split-K=2)
    split_cvt<<<1024, 256, 0, stream>>>(C1, 2048, 2048, a2hi, a2lo);
    split_cvt<<<512, 256, 0, stream>>>(W2, 2048, 2048, w2hi, w2lo);
    gemm_split<<<dim3(8, 16, 2), 256, 0, stream>>>(
        a2hi, a2lo, w2hi, w2lo, P0, 512, 2048, 32, (size_t)1024 * 512);

    // 5) BN2 stats over P0+P1
    bn_stats<<<8, 256, 0, stream>>>(P0, P1, 1024, 512, g2, b2, s2, t2);

    // 6) h3 = relu(bn2(P0+P1)) ; GEMM3 -> d_out
    split_cvt_bnrelu<<<1024, 256, 0, stream>>>(P0, P1, 512, s2, t2, h3hi, h3lo);
    split_cvt<<<256, 256, 0, stream>>>(W3, 512, 512, w3hi, w3lo);
    gemm_split<<<dim3(4, 16, 1), 256, 0, stream>>>(
        h3hi, h3lo, w3hi, w3lo, (float*)d_out, 256, 512, 16, 0);
}

// Round 5
// 231.506 us; speedup vs baseline: 6.1863x; 1.6214x over previous
//
#include <hip/hip_runtime.h>
#include <math.h>

#define SEQL 2048
#define BATCH 1024
#define CHUNK 256
#define NCH 8

typedef short bf16x8 __attribute__((ext_vector_type(8)));
typedef float f32x4 __attribute__((ext_vector_type(4)));

// ---------------------------------------------------------------------------
// bf16 split helpers (RNE)
// ---------------------------------------------------------------------------
__device__ inline unsigned short f2bf(float f) {
    unsigned u = __float_as_uint(f);
    u += 0x7fffu + ((u >> 16) & 1u);
    return (unsigned short)(u >> 16);
}
__device__ inline float bf2f(unsigned short h) {
    return __uint_as_float((unsigned)h << 16);
}

__device__ inline void gl2lds16(const void* g, void* l) {
    __builtin_amdgcn_global_load_lds(
        (const __attribute__((address_space(1))) unsigned int*)g,
        (__attribute__((address_space(3))) unsigned int*)l, 16, 0, 0);
}

// DPP cross-lane add: v += dpp_perm(v).  CTRL: 0xB1=xor1, 0x4E=xor2,
// 0x141=row_half_mirror(xor4), 0x140=row_mirror(xor8), 0x142=row_bcast15.
template<int CTRL>
__device__ inline float dppadd(float v) {
    const int p = __builtin_amdgcn_update_dpp(0, __float_as_int(v), CTRL, 0xF, 0xF, true);
    return v + __int_as_float(p);
}

// ---------------------------------------------------------------------------
// Split-convert: src fp32 [R][K] -> hi/lo bf16 [R][Kp] (zero-padded K..Kp)
// ---------------------------------------------------------------------------
__global__ __launch_bounds__(256) void split_cvt(
    const float* __restrict__ src, int K, int Kp,
    unsigned short* __restrict__ hi, unsigned short* __restrict__ lo)
{
    const int r = blockIdx.x;
    const float* s = src + (size_t)r * K;
    unsigned short* ph = hi + (size_t)r * Kp;
    unsigned short* pl = lo + (size_t)r * Kp;
    for (int k = threadIdx.x; k < Kp; k += 256) {
        const float v = (k < K) ? s[k] : 0.f;
        const unsigned short h = f2bf(v);
        const unsigned short l = f2bf(v - bf2f(h));
        ph[k] = h; pl[k] = l;
    }
}

// Variant: v = relu(s[k]*(P0+P1)+t[k]) -> hi/lo (K == Kp)
__global__ __launch_bounds__(256) void split_cvt_bnrelu(
    const float* __restrict__ P0, const float* __restrict__ P1, int K,
    const float* __restrict__ sc, const float* __restrict__ tc,
    unsigned short* __restrict__ hi, unsigned short* __restrict__ lo)
{
    const int r = blockIdx.x;
    const float* p0 = P0 + (size_t)r * K;
    const float* p1 = P1 + (size_t)r * K;
    unsigned short* ph = hi + (size_t)r * K;
    unsigned short* pl = lo + (size_t)r * K;
    for (int k = threadIdx.x; k < K; k += 256) {
        const float v = fmaxf(fmaf(sc[k], p0[k] + p1[k], tc[k]), 0.f);
        const unsigned short h = f2bf(v);
        const unsigned short l = f2bf(v - bf2f(h));
        ph[k] = h; pl[k] = l;
    }
}

// ---------------------------------------------------------------------------
// Split-bf16 MFMA GEMM (NT): C = A @ B^T, fp32-grade via hi*hi+lo*hi+hi*lo.
// 64x64 tile, BK=32, 4 waves, 16x16x32 MFMA, global_load_lds staging.
// LDS k-slot XOR swizzle (slot ^= (row>>1)&3) applied on BOTH the global
// source (staging) and the fragment read -> 8-way bank conflict becomes 2-way.
// ---------------------------------------------------------------------------
__global__ __launch_bounds__(256) void gemm_split(
    const unsigned short* __restrict__ Ahi, const unsigned short* __restrict__ Alo,
    const unsigned short* __restrict__ Bhi, const unsigned short* __restrict__ Blo,
    float* __restrict__ C, int ldc, int Kp, int ksteps, size_t coff)
{
    __shared__ __attribute__((aligned(16))) unsigned short sA[2][64 * 32];
    __shared__ __attribute__((aligned(16))) unsigned short sB[2][64 * 32];

    const int tid = threadIdx.x;
    const int wave = tid >> 6;
    const int lane = tid & 63;
    const int m0 = blockIdx.y * 64;
    const int n0 = blockIdx.x * 64;
    const int kb = blockIdx.z * ksteps;
    C += (size_t)blockIdx.z * coff;

    // staging: thread t covers row sr = t>>2; physical 16B slot ss = t&3
    // holds global k-slot sg = ss ^ ((sr>>1)&3)  (XOR involution)
    const int sr = tid >> 2, ss = tid & 3;
    const int sg = ss ^ ((sr >> 1) & 3);
    const size_t gk0 = (size_t)kb * 32 + sg * 8;
    const unsigned short* gAhi = Ahi + (size_t)(m0 + sr) * Kp + gk0;
    const unsigned short* gAlo = Alo + (size_t)(m0 + sr) * Kp + gk0;
    const unsigned short* gBhi = Bhi + (size_t)(n0 + sr) * Kp + gk0;
    const unsigned short* gBlo = Blo + (size_t)(n0 + sr) * Kp + gk0;
    const int wbase = wave * 512;

    const int wr = wave >> 1, wc = wave & 1;
    const int li = lane & 15, gq = lane >> 4;
    // physical slot offset for fragment reads (row = ...16*a + li, 16*a%4==0)
    const int pga = (gq ^ ((li >> 1) & 3)) * 8;

    f32x4 acc[2][2];
    #pragma unroll
    for (int i = 0; i < 2; ++i)
        #pragma unroll
        for (int j = 0; j < 2; ++j)
            #pragma unroll
            for (int v = 0; v < 4; ++v) acc[i][j][v] = 0.f;

    for (int kt = 0; kt < ksteps; ++kt) {
        const size_t go = (size_t)kt * 32;
        gl2lds16(gAhi + go, &sA[0][wbase]);
        gl2lds16(gAlo + go, &sA[1][wbase]);
        gl2lds16(gBhi + go, &sB[0][wbase]);
        gl2lds16(gBlo + go, &sB[1][wbase]);
        __syncthreads();

        bf16x8 ah[2], al[2], bh[2], bl[2];
        #pragma unroll
        for (int mi = 0; mi < 2; ++mi) {
            const int idx = (wr * 32 + mi * 16 + li) * 32 + pga;
            ah[mi] = *(const bf16x8*)&sA[0][idx];
            al[mi] = *(const bf16x8*)&sA[1][idx];
        }
        #pragma unroll
        for (int ni = 0; ni < 2; ++ni) {
            const int idx = (wc * 32 + ni * 16 + li) * 32 + pga;
            bh[ni] = *(const bf16x8*)&sB[0][idx];
            bl[ni] = *(const bf16x8*)&sB[1][idx];
        }
        #pragma unroll
        for (int mi = 0; mi < 2; ++mi)
            #pragma unroll
            for (int ni = 0; ni < 2; ++ni) {
                acc[mi][ni] = __builtin_amdgcn_mfma_f32_16x16x32_bf16(ah[mi], bh[ni], acc[mi][ni], 0, 0, 0);
                acc[mi][ni] = __builtin_amdgcn_mfma_f32_16x16x32_bf16(al[mi], bh[ni], acc[mi][ni], 0, 0, 0);
                acc[mi][ni] = __builtin_amdgcn_mfma_f32_16x16x32_bf16(ah[mi], bl[ni], acc[mi][ni], 0, 0, 0);
            }
        __syncthreads();
    }

    #pragma unroll
    for (int mi = 0; mi < 2; ++mi)
        #pragma unroll
        for (int ni = 0; ni < 2; ++ni) {
            const int col = n0 + wc * 32 + ni * 16 + li;
            #pragma unroll
            for (int i = 0; i < 4; ++i) {
                const int row = m0 + wr * 32 + mi * 16 + gq * 4 + i;
                C[(size_t)row * ldc + col] = acc[mi][ni][i];
            }
        }
}

// ---------------------------------------------------------------------------
// Two-pass batchnorm stats: partial sums (grid-saturating), then finalize.
// ---------------------------------------------------------------------------
__global__ __launch_bounds__(256) void bn_part(
    const float* __restrict__ X, const float* __restrict__ X2,
    int rows_per, int ld, float* __restrict__ part)
{
    __shared__ float rs[4][64], rq[4][64];
    const int tid = threadIdx.x;
    const int c = tid & 63, rg4 = tid >> 6;
    const int col = blockIdx.x * 64 + c;
    const int r0 = blockIdx.y * rows_per;
    float sum = 0.f, sq = 0.f;
    for (int r = rg4; r < rows_per; r += 4) {
        const size_t idx = (size_t)(r0 + r) * ld + col;
        float v = X[idx];
        if (X2) v += X2[idx];
        sum += v; sq += v * v;
    }
    rs[rg4][c] = sum; rq[rg4][c] = sq;
    __syncthreads();
    if (rg4 == 0) {
        sum = rs[0][c] + rs[1][c] + rs[2][c] + rs[3][c];
        sq  = rq[0][c] + rq[1][c] + rq[2][c] + rq[3][c];
        part[((size_t)blockIdx.y * 2    ) * ld + col] = sum;
        part[((size_t)blockIdx.y * 2 + 1) * ld + col] = sq;
    }
}

__global__ __launch_bounds__(256) void bn_fin(
    const float* __restrict__ part, int RG, int ld, float inv_rows,
    const float* __restrict__ g, const float* __restrict__ b,
    float* __restrict__ s, float* __restrict__ t)
{
    const int col = blockIdx.x * 256 + threadIdx.x;
    if (col >= ld) return;
    float sum = 0.f, sq = 0.f;
    for (int z = 0; z < RG; ++z) {
        sum += part[((size_t)z * 2    ) * ld + col];
        sq  += part[((size_t)z * 2 + 1) * ld + col];
    }
    const float mean = sum * inv_rows;
    const float var = fmaxf(sq * inv_rows - mean * mean, 0.f);
    const float rstd = 1.0f / sqrtf(var + 1e-5f);
    const float sv = g[col] * rstd;
    s[col] = sv;
    t[col] = b[col] - mean * sv;
}

// ---------------------------------------------------------------------------
// Chunked-parallel mamba scan, v4: DPP reduction replaces the DS shuffle tree.
// ---------------------------------------------------------------------------
__global__ __launch_bounds__(256, 4) void mamba_scan4(
    float* __restrict__ Y,
    const float* __restrict__ s1, const float* __restrict__ t1,
    const float* __restrict__ Win, const float* __restrict__ convw,
    const float* __restrict__ convb, const float* __restrict__ Wx,
    const float* __restrict__ Wdt, const float* __restrict__ bdt,
    const float* __restrict__ Alog, const float* __restrict__ Dp,
    const float* __restrict__ Wout)
{
    __shared__ __align__(16) float4 pk[SEQL];   // 32 KB (dt0,dt1,x0,x1)
    __shared__ float Ps[NCH][32];
    __shared__ float Ss[NCH][32];
    __shared__ float Hin[NCH][32];

    const int tid = threadIdx.x;
    const int row = blockIdx.x;
    float* yrow = Y + (size_t)row * SEQL;

    float u_sav[8];

    // ---- phase A': steps [8*tid, 8*tid+8), conv window in registers ------
    {
        const int l0 = tid * 8;
        float4 ym = {0.f,0.f,0.f,0.f}, sm = {0.f,0.f,0.f,0.f}, tm = {0.f,0.f,0.f,0.f};
        if (tid > 0) {
            ym = *reinterpret_cast<const float4*>(&yrow[l0 - 4]);
            sm = *reinterpret_cast<const float4*>(&s1[l0 - 4]);
            tm = *reinterpret_cast<const float4*>(&t1[l0 - 4]);
        }
        const float4 y0 = *reinterpret_cast<const float4*>(&yrow[l0]);
        const float4 s0 = *reinterpret_cast<const float4*>(&s1[l0]);
        const float4 t0 = *reinterpret_cast<const float4*>(&t1[l0]);
        const float4 y1 = *reinterpret_cast<const float4*>(&yrow[l0 + 4]);
        const float4 s4 = *reinterpret_cast<const float4*>(&s1[l0 + 4]);
        const float4 t4 = *reinterpret_cast<const float4*>(&t1[l0 + 4]);

        float ua[12];
        ua[0]  = fmaf(sm.x, ym.x, tm.x);
        ua[1]  = fmaf(sm.y, ym.y, tm.y);
        ua[2]  = fmaf(sm.z, ym.z, tm.z);
        ua[3]  = fmaf(sm.w, ym.w, tm.w);
        ua[4]  = fmaf(s0.x, y0.x, t0.x);
        ua[5]  = fmaf(s0.y, y0.y, t0.y);
        ua[6]  = fmaf(s0.z, y0.z, t0.z);
        ua[7]  = fmaf(s0.w, y0.w, t0.w);
        ua[8]  = fmaf(s4.x, y1.x, t4.x);
        ua[9]  = fmaf(s4.y, y1.y, t4.y);
        ua[10] = fmaf(s4.z, y1.z, t4.z);
        ua[11] = fmaf(s4.w, y1.w, t4.w);

        const float wi0 = Win[0], wi1 = Win[1];
        const float cw00 = convw[0], cw01 = convw[1], cw02 = convw[2], cw03 = convw[3];
        const float cw10 = convw[4], cw11 = convw[5], cw12 = convw[6], cw13 = convw[7];
        const float cb0 = convb[0], cb1 = convb[1];
        const float wx00 = Wx[0], wx01 = Wx[1];
        const float wdt0 = Wdt[0], wdt1 = Wdt[1];
        const float bdt0 = bdt[0], bdt1 = bdt[1];

        #pragma unroll
        for (int j = 0; j < 8; ++j) {
            const float u0 = ua[j + 4], um1 = ua[j + 3], um2 = ua[j + 2], um3 = ua[j + 1];
            const float c0 = fmaf(wi0, cw00 * um3 + cw01 * um2 + cw02 * um1 + cw03 * u0, cb0);
            const float c1 = fmaf(wi1, cw10 * um3 + cw11 * um2 + cw12 * um1 + cw13 * u0, cb1);
            const float xs0 = c0 / (1.f + __expf(-c0));
            const float xs1 = c1 / (1.f + __expf(-c1));
            const float d0 = xs0 * wx00 + xs1 * wx01;
            const float dt0 = __logf(1.f + __expf(fmaf(d0, wdt0, bdt0)));
            const float dt1 = __logf(1.f + __expf(fmaf(d0, wdt1, bdt1)));
            float4 rec; rec.x = dt0; rec.y = dt1; rec.z = xs0; rec.w = xs1;
            pk[l0 + j] = rec;
            u_sav[j] = u0;
        }
    }
    __syncthreads();

    // ---- lane decomposition ----------------------------------------------
    const int c  = tid >> 5;       // chunk = half-wave
    const int l5 = tid & 31;
    const int e  = l5 >> 4;
    const int n  = l5 & 15;
    const int base = c * CHUNK;

    const float Aen  = -__expf(Alog[e * 16 + n]);
    const float wxB0 = Wx[(1 + n) * 2 + 0],  wxB1 = Wx[(1 + n) * 2 + 1];
    const float wxC0 = Wx[(17 + n) * 2 + 0], wxC1 = Wx[(17 + n) * 2 + 1];

    // ---- phase A'': local scan, h_in = 0 ---------------------------------
    {
        float h = 0.f, p = 1.f;
        for (int i0 = 0; i0 < CHUNK; i0 += 8) {
            #pragma unroll
            for (int j = 0; j < 8; ++j) {
                const float4 v = pk[base + i0 + j];
                const float dte = e ? v.y : v.x;
                const float xe  = e ? v.w : v.z;
                const float Bn = fmaf(v.z, wxB0, v.w * wxB1);
                const float dA = __expf(dte * Aen);
                h = fmaf(h, dA, dte * xe * Bn);
                p *= dA;
            }
        }
        Ps[c][l5] = p;
        Ss[c][l5] = h;
    }
    __syncthreads();

    // ---- phase B: serial chunk combine -----------------------------------
    if (tid < 32) {
        float H = 0.f;
        #pragma unroll
        for (int cc = 0; cc < NCH; ++cc) {
            Hin[cc][tid] = H;
            H = fmaf(Ps[cc][tid], H, Ss[cc][tid]);
        }
    }
    __syncthreads();

    // ---- phase C: seeded re-scan + output --------------------------------
    // q = (h*Cn + De*xe/16) * sz_e summed over the 32-lane chunk via DPP
    // equals sum_e [ (sum_n h*Cn) + De*xe ] * sz_e  (16 n-lanes per e).
    {
        const float De16 = Dp[e] * 0.0625f;
        const float woute = Wout[e];
        const float wz = Win[2 + e];
        const int srcbase = tid & 32;
        float h = Hin[c][l5];
        for (int i0 = 0; i0 < CHUNK; i0 += 8) {
            #pragma unroll
            for (int j = 0; j < 8; ++j) {
                const int i = i0 + j;
                const float4 v = pk[base + i];
                const float dte = e ? v.y : v.x;
                const float xe  = e ? v.w : v.z;
                const float Bn = fmaf(v.z, wxB0, v.w * wxB1);
                const float Cn = fmaf(v.z, wxC0, v.w * wxC1);
                const float dA = __expf(dte * Aen);
                h = fmaf(h, dA, dte * xe * Bn);
                const float uu = __shfl(u_sav[j], srcbase + (i >> 3), 64);
                const float z = uu * wz;
                const float sz = (z / (1.f + __expf(-z))) * woute;
                float q = fmaf(h, Cn, De16 * xe) * sz;
                q = dppadd<0xB1>(q);    // xor1 (quad_perm)
                q = dppadd<0x4E>(q);    // xor2 (quad_perm)
                q = dppadd<0x141>(q);   // xor4 (row_half_mirror)
                q = dppadd<0x140>(q);   // xor8 (row_mirror)
                q = dppadd<0x142>(q);   // row_bcast15: lanes 16..31 get total
                if (l5 == 16) yrow[base + i] = q;
            }
        }
    }
}

// ---------------------------------------------------------------------------
extern "C" void kernel_launch(void* const* d_in, const int* in_sizes, int n_in,
                              void* d_out, int out_size, void* d_ws, size_t ws_size,
                              hipStream_t stream)
{
    const float* x     = (const float*)d_in[0];
    const float* W1    = (const float*)d_in[1];
    const float* g1    = (const float*)d_in[2];
    const float* b1    = (const float*)d_in[3];
    const float* Win   = (const float*)d_in[4];
    const float* convw = (const float*)d_in[5];
    const float* convb = (const float*)d_in[6];
    const float* Wx    = (const float*)d_in[7];
    const float* Wdt   = (const float*)d_in[8];
    const float* bdt   = (const float*)d_in[9];
    const float* Alog  = (const float*)d_in[10];
    const float* Dp    = (const float*)d_in[11];
    const float* Wout  = (const float*)d_in[12];
    const float* W2    = (const float*)d_in[13];
    const float* g2    = (const float*)d_in[14];
    const float* b2    = (const float*)d_in[15];
    const float* W3    = (const float*)d_in[16];

    unsigned char* base = (unsigned char*)d_ws;
    float* C1 = (float*)(base + 0);                        // 8,388,608 B
    float* P0 = (float*)(base + 8388608);                  // 2,097,152
    float* P1 = (float*)(base + 10485760);                 // 2,097,152
    float* s1 = (float*)(base + 12582912);
    float* t1 = (float*)(base + 12591104);
    float* s2 = (float*)(base + 12599296);
    float* t2 = (float*)(base + 12601344);
    unsigned char* pX = base + 12603392;
    unsigned short* xhi  = (unsigned short*)(pX);
    unsigned short* xlo  = (unsigned short*)(pX + 4194304);
    unsigned short* a2hi = (unsigned short*)(pX);
    unsigned short* a2lo = (unsigned short*)(pX + 4194304);
    // bn partials reuse pX (dead between GEMM consumption and next split)
    float* bnp = (float*)pX;
    unsigned char* pW = base + 20992000;
    unsigned short* w1hi = (unsigned short*)(pW);
    unsigned short* w1lo = (unsigned short*)(pW + 7340032);
    unsigned short* w2hi = (unsigned short*)(pW);
    unsigned short* w2lo = (unsigned short*)(pW + 2097152);
    unsigned short* h3hi = (unsigned short*)(pW + 4194304);
    unsigned short* h3lo = (unsigned short*)(pW + 5242880);
    unsigned short* w3hi = (unsigned short*)(pW + 6291456);
    unsigned short* w3lo = (unsigned short*)(pW + 6553600);

    // 1) split x, W1 ; GEMM1: C1 = x @ W1^T
    split_cvt<<<1024, 256, 0, stream>>>(x, 1775, 1792, xhi, xlo);
    split_cvt<<<2048, 256, 0, stream>>>(W1, 1775, 1792, w1hi, w1lo);
    gemm_split<<<dim3(32, 16, 1), 256, 0, stream>>>(
        xhi, xlo, w1hi, w1lo, C1, 2048, 1792, 56, 0);

    // 2) BN1 stats (two-pass; partials in pX — xhi is dead after GEMM1)
    bn_part<<<dim3(32, 8), 256, 0, stream>>>(C1, nullptr, 128, 2048, bnp);
    bn_fin<<<8, 256, 0, stream>>>(bnp, 8, 2048, 1.0f / 1024.f, g1, b1, s1, t1);

    // 3) mamba scan (in place over C1)
    mamba_scan4<<<1024, 256, 0, stream>>>(C1, s1, t1, Win, convw, convb,
                                          Wx, Wdt, bdt, Alog, Dp, Wout);

    // 4) split C1, W2 ; GEMM2 (split-K=2)
    split_cvt<<<1024, 256, 0, stream>>>(C1, 2048, 2048, a2hi, a2lo);
    split_cvt<<<512, 256, 0, stream>>>(W2, 2048, 2048, w2hi, w2lo);
    gemm_split<<<dim3(8, 16, 2), 256, 0, stream>>>(
        a2hi, a2lo, w2hi, w2lo, P0, 512, 2048, 32, (size_t)1024 * 512);

    // 5) BN2 stats over P0+P1 (two-pass; partials in pX — a2 dead after GEMM2)
    bn_part<<<dim3(8, 16), 256, 0, stream>>>(P0, P1, 64, 512, bnp);
    bn_fin<<<2, 256, 0, stream>>>(bnp, 16, 512, 1.0f / 1024.f, g2, b2, s2, t2);

    // 6) h3 = relu(bn2(P0+P1)) ; GEMM3 -> d_out
    split_cvt_bnrelu<<<1024, 256, 0, stream>>>(P0, P1, 512, s2, t2, h3hi, h3lo);
    split_cvt<<<256, 256, 0, stream>>>(W3, 512, 512, w3hi, w3lo);
    gemm_split<<<dim3(4, 16, 1), 256, 0, stream>>>(
        h3hi, h3lo, w3hi, w3lo, (float*)d_out, 256, 512, 16, 0);
}

// Round 6
// 175.300 us; speedup vs baseline: 8.1698x; 1.3206x over previous
//
#include <hip/hip_runtime.h>
#include <math.h>

#define SEQL 2048
#define BATCH 1024
#define CHUNK 256
#define NCH 8

typedef _Float16 f16x8 __attribute__((ext_vector_type(8)));
typedef _Float16 f16x4 __attribute__((ext_vector_type(4)));
typedef float f32x4 __attribute__((ext_vector_type(4)));

// ---------------------------------------------------------------------------
// fp16 pack/unpack helpers (RNE via v_cvt_f16_f32)
// ---------------------------------------------------------------------------
__device__ inline unsigned short f2h(float f) {
    _Float16 h = (_Float16)f;
    return *reinterpret_cast<unsigned short*>(&h);
}
__device__ inline float hlo(float packed) {
    unsigned short s = (unsigned short)__float_as_uint(packed);
    _Float16 h = *reinterpret_cast<_Float16*>(&s);
    return (float)h;
}
__device__ inline float hhi(float packed) {
    unsigned short s = (unsigned short)(__float_as_uint(packed) >> 16);
    _Float16 h = *reinterpret_cast<_Float16*>(&s);
    return (float)h;
}
__device__ inline float packh2(float a, float b) {
    return __uint_as_float((unsigned)f2h(a) | ((unsigned)f2h(b) << 16));
}

__device__ inline void gl2lds16(const void* g, void* l) {
    __builtin_amdgcn_global_load_lds(
        (const __attribute__((address_space(1))) unsigned int*)g,
        (__attribute__((address_space(3))) unsigned int*)l, 16, 0, 0);
}

// DPP cross-lane add: v += dpp_perm(v).
template<int CTRL>
__device__ inline float dppadd(float v) {
    const int p = __builtin_amdgcn_update_dpp(0, __float_as_int(v), CTRL, 0xF, 0xF, true);
    return v + __int_as_float(p);
}

// ---------------------------------------------------------------------------
// Merged fp32->fp16 convert for x (1024 rows, K 1775->1792 zero-pad) and
// W1 (2048 rows, same K/Kp).
// ---------------------------------------------------------------------------
__global__ __launch_bounds__(256) void cvt_xw1(
    const float* __restrict__ x, const float* __restrict__ W1,
    _Float16* __restrict__ xh, _Float16* __restrict__ w1h)
{
    const int bid = blockIdx.x;
    const float* src;
    _Float16* dst;
    if (bid < 1024) { src = x + (size_t)bid * 1775;          dst = xh  + (size_t)bid * 1792; }
    else            { src = W1 + (size_t)(bid - 1024) * 1775; dst = w1h + (size_t)(bid - 1024) * 1792; }
    f16x4* dst4 = reinterpret_cast<f16x4*>(dst);
    for (int i = threadIdx.x; i < 448; i += 256) {
        const int k = i * 4;
        float4 v = {0.f, 0.f, 0.f, 0.f};
        if (k + 3 < 1775) v = *reinterpret_cast<const float4*>(&src[k]);
        else {
            if (k     < 1775) v.x = src[k];
            if (k + 1 < 1775) v.y = src[k + 1];
            if (k + 2 < 1775) v.z = src[k + 2];
        }
        f16x4 o; o[0] = (_Float16)v.x; o[1] = (_Float16)v.y; o[2] = (_Float16)v.z; o[3] = (_Float16)v.w;
        dst4[i] = o;
    }
}

// Merged convert for W2 (512 rows, K=2048) and W3 (256 rows, K=512).
__global__ __launch_bounds__(256) void cvt_w23(
    const float* __restrict__ W2, const float* __restrict__ W3,
    _Float16* __restrict__ w2h, _Float16* __restrict__ w3h)
{
    const int bid = blockIdx.x;
    const float* src;
    _Float16* dst;
    int nvec;
    if (bid < 512) { src = W2 + (size_t)bid * 2048;        dst = w2h + (size_t)bid * 2048; nvec = 512; }
    else           { src = W3 + (size_t)(bid - 512) * 512; dst = w3h + (size_t)(bid - 512) * 512; nvec = 128; }
    f16x4* dst4 = reinterpret_cast<f16x4*>(dst);
    for (int i = threadIdx.x; i < nvec; i += 256) {
        const float4 v = reinterpret_cast<const float4*>(src)[i];
        f16x4 o; o[0] = (_Float16)v.x; o[1] = (_Float16)v.y; o[2] = (_Float16)v.z; o[3] = (_Float16)v.w;
        dst4[i] = o;
    }
}

// h3 = relu(bn2(P0+P1)) -> fp16.  2 rows per block, K=512.
__global__ __launch_bounds__(256) void cvt_bnrelu(
    const float* __restrict__ P0, const float* __restrict__ P1,
    const float* __restrict__ sc, const float* __restrict__ tc,
    _Float16* __restrict__ h3)
{
    const int row = blockIdx.x * 2 + (threadIdx.x >> 7);
    const int i = threadIdx.x & 127;
    const float4 p0 = reinterpret_cast<const float4*>(P0 + (size_t)row * 512)[i];
    const float4 p1 = reinterpret_cast<const float4*>(P1 + (size_t)row * 512)[i];
    const float4 sv = reinterpret_cast<const float4*>(sc)[i];
    const float4 tv = reinterpret_cast<const float4*>(tc)[i];
    f16x4 o;
    o[0] = (_Float16)fmaxf(fmaf(sv.x, p0.x + p1.x, tv.x), 0.f);
    o[1] = (_Float16)fmaxf(fmaf(sv.y, p0.y + p1.y, tv.y), 0.f);
    o[2] = (_Float16)fmaxf(fmaf(sv.z, p0.z + p1.z, tv.z), 0.f);
    o[3] = (_Float16)fmaxf(fmaf(sv.w, p0.w + p1.w, tv.w), 0.f);
    reinterpret_cast<f16x4*>(h3 + (size_t)row * 512)[i] = o;
}

// ---------------------------------------------------------------------------
// fp16 MFMA GEMM (NT): C[m][n] = sum_k A[m][k]*B[n][k]. 64x64 tile, BK=64,
// 4 waves, 16x16x32_f16 MFMA, global_load_lds staging, XOR slot swizzle
// (slot ^= row&7) applied on BOTH the pre-swizzled global source and the
// fragment read (rows are 128B -> unswizzled would be a 16-way conflict).
// Optional split-K over blockIdx.z.
// ---------------------------------------------------------------------------
__global__ __launch_bounds__(256) void gemm_f16(
    const _Float16* __restrict__ A, const _Float16* __restrict__ B,
    float* __restrict__ C, int ldc, int Kp, int ksteps, size_t coff)
{
    __shared__ __attribute__((aligned(16))) _Float16 sA[64 * 64];  // 8 KB
    __shared__ __attribute__((aligned(16))) _Float16 sB[64 * 64];  // 8 KB

    const int tid = threadIdx.x;
    const int wave = tid >> 6;
    const int lane = tid & 63;
    const int m0 = blockIdx.y * 64;
    const int n0 = blockIdx.x * 64;
    C += (size_t)blockIdx.z * coff;

    // staging: thread t covers row (t>>3) (+32 for round 1), physical 16B
    // slot (t&7); it loads global k-slot  gslot = (t&7) ^ (row&7).
    const int srow = tid >> 3;          // 0..31
    const int pslot = tid & 7;
    const int gslot = pslot ^ (srow & 7);
    const size_t gk0 = (size_t)blockIdx.z * ksteps * 64 + gslot * 8;
    const _Float16* gA0 = A + (size_t)(m0 + srow) * Kp + gk0;
    const _Float16* gA1 = A + (size_t)(m0 + 32 + srow) * Kp + gk0;
    const _Float16* gB0 = B + (size_t)(n0 + srow) * Kp + gk0;
    const _Float16* gB1 = B + (size_t)(n0 + 32 + srow) * Kp + gk0;
    const int wdst = wave * 512;        // halves: wave*1024B

    const int wr = wave >> 1, wc = wave & 1;
    const int li = lane & 15, gq = lane >> 4;
    // physical slot for fragment reads: (gq + 4*ks) ^ (li&7)  (row&7 == li&7)
    const int p0s = (gq    ) ^ (li & 7);
    const int p1s = (gq + 4) ^ (li & 7);

    f32x4 acc[2][2];
    #pragma unroll
    for (int i = 0; i < 2; ++i)
        #pragma unroll
        for (int j = 0; j < 2; ++j)
            #pragma unroll
            for (int v = 0; v < 4; ++v) acc[i][j][v] = 0.f;

    for (int kt = 0; kt < ksteps; ++kt) {
        const size_t go = (size_t)kt * 64;
        gl2lds16(gA0 + go, &sA[wdst]);
        gl2lds16(gA1 + go, &sA[2048 + wdst]);
        gl2lds16(gB0 + go, &sB[wdst]);
        gl2lds16(gB1 + go, &sB[2048 + wdst]);
        __syncthreads();

        f16x8 af[2][2], bg[2][2];
        #pragma unroll
        for (int mi = 0; mi < 2; ++mi) {
            const int rb = (wr * 32 + mi * 16 + li) * 64;
            af[mi][0] = *(const f16x8*)&sA[rb + p0s * 8];
            af[mi][1] = *(const f16x8*)&sA[rb + p1s * 8];
        }
        #pragma unroll
        for (int ni = 0; ni < 2; ++ni) {
            const int rb = (wc * 32 + ni * 16 + li) * 64;
            bg[ni][0] = *(const f16x8*)&sB[rb + p0s * 8];
            bg[ni][1] = *(const f16x8*)&sB[rb + p1s * 8];
        }
        #pragma unroll
        for (int mi = 0; mi < 2; ++mi)
            #pragma unroll
            for (int ni = 0; ni < 2; ++ni) {
                acc[mi][ni] = __builtin_amdgcn_mfma_f32_16x16x32_f16(af[mi][0], bg[ni][0], acc[mi][ni], 0, 0, 0);
                acc[mi][ni] = __builtin_amdgcn_mfma_f32_16x16x32_f16(af[mi][1], bg[ni][1], acc[mi][ni], 0, 0, 0);
            }
        __syncthreads();
    }

    #pragma unroll
    for (int mi = 0; mi < 2; ++mi)
        #pragma unroll
        for (int ni = 0; ni < 2; ++ni) {
            const int col = n0 + wc * 32 + ni * 16 + li;
            #pragma unroll
            for (int i = 0; i < 4; ++i) {
                const int row = m0 + wr * 32 + mi * 16 + gq * 4 + i;
                C[(size_t)row * ldc + col] = acc[mi][ni][i];
            }
        }
}

// ---------------------------------------------------------------------------
// Two-pass batchnorm stats.
// ---------------------------------------------------------------------------
__global__ __launch_bounds__(256) void bn_part(
    const float* __restrict__ X, const float* __restrict__ X2,
    int rows_per, int ld, float* __restrict__ part)
{
    __shared__ float rs[4][64], rq[4][64];
    const int tid = threadIdx.x;
    const int c = tid & 63, rg4 = tid >> 6;
    const int col = blockIdx.x * 64 + c;
    const int r0 = blockIdx.y * rows_per;
    float sum = 0.f, sq = 0.f;
    for (int r = rg4; r < rows_per; r += 4) {
        const size_t idx = (size_t)(r0 + r) * ld + col;
        float v = X[idx];
        if (X2) v += X2[idx];
        sum += v; sq += v * v;
    }
    rs[rg4][c] = sum; rq[rg4][c] = sq;
    __syncthreads();
    if (rg4 == 0) {
        sum = rs[0][c] + rs[1][c] + rs[2][c] + rs[3][c];
        sq  = rq[0][c] + rq[1][c] + rq[2][c] + rq[3][c];
        part[((size_t)blockIdx.y * 2    ) * ld + col] = sum;
        part[((size_t)blockIdx.y * 2 + 1) * ld + col] = sq;
    }
}

__global__ __launch_bounds__(256) void bn_fin(
    const float* __restrict__ part, int RG, int ld, float inv_rows,
    const float* __restrict__ g, const float* __restrict__ b,
    float* __restrict__ s, float* __restrict__ t)
{
    const int col = blockIdx.x * 256 + threadIdx.x;
    if (col >= ld) return;
    float sum = 0.f, sq = 0.f;
    for (int z = 0; z < RG; ++z) {
        sum += part[((size_t)z * 2    ) * ld + col];
        sq  += part[((size_t)z * 2 + 1) * ld + col];
    }
    const float mean = sum * inv_rows;
    const float var = fmaxf(sq * inv_rows - mean * mean, 0.f);
    const float rstd = 1.0f / sqrtf(var + 1e-5f);
    const float sv = g[col] * rstd;
    s[col] = sv;
    t[col] = b[col] - mean * sv;
}

// ---------------------------------------------------------------------------
// Chunked-parallel mamba scan, v5:
//  - pk 16B/step: (dt0 f32, dt1 f32, xs half2, gate half2) — one broadcast
//    ds_read_b128 per step; the silu(z)·wout gate is precomputed in A'.
//  - output written directly as fp16 into a2 (GEMM2's A operand).
// ---------------------------------------------------------------------------
__global__ __launch_bounds__(256, 4) void mamba_scan5(
    const float* __restrict__ Y, _Float16* __restrict__ a2,
    const float* __restrict__ s1, const float* __restrict__ t1,
    const float* __restrict__ Win, const float* __restrict__ convw,
    const float* __restrict__ convb, const float* __restrict__ Wx,
    const float* __restrict__ Wdt, const float* __restrict__ bdt,
    const float* __restrict__ Alog, const float* __restrict__ Dp,
    const float* __restrict__ Wout)
{
    __shared__ __align__(16) float4 pk[SEQL];   // 32 KB
    __shared__ float Ps[NCH][32];
    __shared__ float Ss[NCH][32];
    __shared__ float Hin[NCH][32];

    const int tid = threadIdx.x;
    const int row = blockIdx.x;
    const float* yrow = Y + (size_t)row * SEQL;
    _Float16* a2row = a2 + (size_t)row * SEQL;

    // ---- phase A': steps [8*tid, 8*tid+8) ---------------------------------
    {
        const int l0 = tid * 8;
        float4 ym = {0.f,0.f,0.f,0.f}, sm = {0.f,0.f,0.f,0.f}, tm = {0.f,0.f,0.f,0.f};
        if (tid > 0) {
            ym = *reinterpret_cast<const float4*>(&yrow[l0 - 4]);
            sm = *reinterpret_cast<const float4*>(&s1[l0 - 4]);
            tm = *reinterpret_cast<const float4*>(&t1[l0 - 4]);
        }
        const float4 y0 = *reinterpret_cast<const float4*>(&yrow[l0]);
        const float4 s0 = *reinterpret_cast<const float4*>(&s1[l0]);
        const float4 t0 = *reinterpret_cast<const float4*>(&t1[l0]);
        const float4 y1 = *reinterpret_cast<const float4*>(&yrow[l0 + 4]);
        const float4 s4 = *reinterpret_cast<const float4*>(&s1[l0 + 4]);
        const float4 t4 = *reinterpret_cast<const float4*>(&t1[l0 + 4]);

        float ua[12];
        ua[0]  = fmaf(sm.x, ym.x, tm.x);
        ua[1]  = fmaf(sm.y, ym.y, tm.y);
        ua[2]  = fmaf(sm.z, ym.z, tm.z);
        ua[3]  = fmaf(sm.w, ym.w, tm.w);
        ua[4]  = fmaf(s0.x, y0.x, t0.x);
        ua[5]  = fmaf(s0.y, y0.y, t0.y);
        ua[6]  = fmaf(s0.z, y0.z, t0.z);
        ua[7]  = fmaf(s0.w, y0.w, t0.w);
        ua[8]  = fmaf(s4.x, y1.x, t4.x);
        ua[9]  = fmaf(s4.y, y1.y, t4.y);
        ua[10] = fmaf(s4.z, y1.z, t4.z);
        ua[11] = fmaf(s4.w, y1.w, t4.w);

        const float wi0 = Win[0], wi1 = Win[1];
        const float wz0 = Win[2], wz1 = Win[3];
        const float wo0 = Wout[0], wo1 = Wout[1];
        const float cw00 = convw[0], cw01 = convw[1], cw02 = convw[2], cw03 = convw[3];
        const float cw10 = convw[4], cw11 = convw[5], cw12 = convw[6], cw13 = convw[7];
        const float cb0 = convb[0], cb1 = convb[1];
        const float wx00 = Wx[0], wx01 = Wx[1];
        const float wdt0 = Wdt[0], wdt1 = Wdt[1];
        const float bdt0 = bdt[0], bdt1 = bdt[1];

        #pragma unroll
        for (int j = 0; j < 8; ++j) {
            const float u0 = ua[j + 4], um1 = ua[j + 3], um2 = ua[j + 2], um3 = ua[j + 1];
            const float c0 = fmaf(wi0, cw00 * um3 + cw01 * um2 + cw02 * um1 + cw03 * u0, cb0);
            const float c1 = fmaf(wi1, cw10 * um3 + cw11 * um2 + cw12 * um1 + cw13 * u0, cb1);
            const float xs0 = c0 / (1.f + __expf(-c0));
            const float xs1 = c1 / (1.f + __expf(-c1));
            const float d0 = xs0 * wx00 + xs1 * wx01;
            const float dt0 = __logf(1.f + __expf(fmaf(d0, wdt0, bdt0)));
            const float dt1 = __logf(1.f + __expf(fmaf(d0, wdt1, bdt1)));
            const float z0 = u0 * wz0, z1 = u0 * wz1;
            const float g0 = (z0 / (1.f + __expf(-z0))) * wo0;
            const float g1 = (z1 / (1.f + __expf(-z1))) * wo1;
            float4 rec;
            rec.x = dt0; rec.y = dt1;
            rec.z = packh2(xs0, xs1);
            rec.w = packh2(g0, g1);
            pk[l0 + j] = rec;
        }
    }
    __syncthreads();

    // ---- lane decomposition ----------------------------------------------
    const int c  = tid >> 5;       // chunk = half-wave
    const int l5 = tid & 31;
    const int e  = l5 >> 4;
    const int n  = l5 & 15;
    const int base = c * CHUNK;

    const float Aen  = -__expf(Alog[e * 16 + n]);
    const float wxB0 = Wx[(1 + n) * 2 + 0],  wxB1 = Wx[(1 + n) * 2 + 1];
    const float wxC0 = Wx[(17 + n) * 2 + 0], wxC1 = Wx[(17 + n) * 2 + 1];

    // ---- phase A'': local scan, h_in = 0 ---------------------------------
    {
        float h = 0.f, p = 1.f;
        for (int i0 = 0; i0 < CHUNK; i0 += 8) {
            #pragma unroll
            for (int j = 0; j < 8; ++j) {
                const float4 v = pk[base + i0 + j];
                const float dte = e ? v.y : v.x;
                const float x0 = hlo(v.z), x1 = hhi(v.z);
                const float Bn = fmaf(x0, wxB0, x1 * wxB1);
                const float xe = e ? x1 : x0;
                const float dA = __expf(dte * Aen);
                h = fmaf(h, dA, dte * xe * Bn);
                p *= dA;
            }
        }
        Ps[c][l5] = p;
        Ss[c][l5] = h;
    }
    __syncthreads();

    // ---- phase B: serial chunk combine -----------------------------------
    if (tid < 32) {
        float H = 0.f;
        #pragma unroll
        for (int cc = 0; cc < NCH; ++cc) {
            Hin[cc][tid] = H;
            H = fmaf(Ps[cc][tid], H, Ss[cc][tid]);
        }
    }
    __syncthreads();

    // ---- phase C: seeded re-scan + fp16 output ----------------------------
    {
        const float De16 = Dp[e] * 0.0625f;
        float h = Hin[c][l5];
        for (int i0 = 0; i0 < CHUNK; i0 += 8) {
            #pragma unroll
            for (int j = 0; j < 8; ++j) {
                const int i = i0 + j;
                const float4 v = pk[base + i];
                const float dte = e ? v.y : v.x;
                const float x0 = hlo(v.z), x1 = hhi(v.z);
                const float Bn = fmaf(x0, wxB0, x1 * wxB1);
                const float Cn = fmaf(x0, wxC0, x1 * wxC1);
                const float xe = e ? x1 : x0;
                const float ge = e ? hhi(v.w) : hlo(v.w);
                const float dA = __expf(dte * Aen);
                h = fmaf(h, dA, dte * xe * Bn);
                float q = fmaf(h, Cn, De16 * xe) * ge;
                q = dppadd<0xB1>(q);    // xor1
                q = dppadd<0x4E>(q);    // xor2
                q = dppadd<0x141>(q);   // xor4 (row_half_mirror)
                q = dppadd<0x140>(q);   // xor8 (row_mirror)
                q = dppadd<0x142>(q);   // row_bcast15 -> lanes 16..31
                if (l5 == 16) a2row[base + i] = (_Float16)q;
            }
        }
    }
}

// ---------------------------------------------------------------------------
extern "C" void kernel_launch(void* const* d_in, const int* in_sizes, int n_in,
                              void* d_out, int out_size, void* d_ws, size_t ws_size,
                              hipStream_t stream)
{
    const float* x     = (const float*)d_in[0];
    const float* W1    = (const float*)d_in[1];
    const float* g1    = (const float*)d_in[2];
    const float* b1    = (const float*)d_in[3];
    const float* Win   = (const float*)d_in[4];
    const float* convw = (const float*)d_in[5];
    const float* convb = (const float*)d_in[6];
    const float* Wx    = (const float*)d_in[7];
    const float* Wdt   = (const float*)d_in[8];
    const float* bdt   = (const float*)d_in[9];
    const float* Alog  = (const float*)d_in[10];
    const float* Dp    = (const float*)d_in[11];
    const float* Wout  = (const float*)d_in[12];
    const float* W2    = (const float*)d_in[13];
    const float* g2    = (const float*)d_in[14];
    const float* b2    = (const float*)d_in[15];
    const float* W3    = (const float*)d_in[16];

    unsigned char* base = (unsigned char*)d_ws;
    float* C1 = (float*)(base + 0);                        // 8,388,608 B
    float* P0 = (float*)(base + 8388608);                  // 2,097,152
    float* P1 = (float*)(base + 10485760);                 // 2,097,152
    float* s1 = (float*)(base + 12582912);
    float* t1 = (float*)(base + 12591104);
    float* s2 = (float*)(base + 12599296);
    float* t2 = (float*)(base + 12601344);
    // pool X (8.39 MB): xh (3.67 MB) until GEMM1; then a2 (4.19 MB);
    // bn partials live at +4.5 MiB (disjoint from both).
    unsigned char* pX = base + 12603392;
    _Float16* xh = (_Float16*)pX;
    _Float16* a2 = (_Float16*)pX;
    float* bnp = (float*)(pX + 4718592);
    // pool W (14.68 MB): w1h (7.34 MB) until GEMM1; then w2h/w3h/h3h.
    unsigned char* pW = base + 20992000;
    _Float16* w1h = (_Float16*)pW;
    _Float16* w2h = (_Float16*)pW;                         // 2,097,152 B
    _Float16* w3h = (_Float16*)(pW + 2097152);             //   262,144 B
    _Float16* h3h = (_Float16*)(pW + 2359296);             // 1,048,576 B

    // 1) cvt x, W1 -> fp16 (merged)
    cvt_xw1<<<3072, 256, 0, stream>>>(x, W1, xh, w1h);

    // 2) GEMM1: C1 = x @ W1^T   (M=1024, N=2048, Kp=1792, BK=64)
    gemm_f16<<<dim3(32, 16, 1), 256, 0, stream>>>(xh, w1h, C1, 2048, 1792, 28, 0);

    // 3) BN1 stats
    bn_part<<<dim3(32, 8), 256, 0, stream>>>(C1, nullptr, 128, 2048, bnp);
    bn_fin<<<8, 256, 0, stream>>>(bnp, 8, 2048, 1.0f / 1024.f, g1, b1, s1, t1);

    // 4) cvt W2, W3 -> fp16 (merged; w1h region now dead)
    cvt_w23<<<768, 256, 0, stream>>>(W2, W3, w2h, w3h);

    // 5) mamba scan: reads C1, writes a2 (fp16)
    mamba_scan5<<<1024, 256, 0, stream>>>(C1, a2, s1, t1, Win, convw, convb,
                                          Wx, Wdt, bdt, Alog, Dp, Wout);

    // 6) GEMM2 (split-K=2): P0/P1 = a2 @ W2^T  (1024x512, K=2048)
    gemm_f16<<<dim3(8, 16, 2), 256, 0, stream>>>(a2, w2h, P0, 512, 2048, 16,
                                                 (size_t)1024 * 512);

    // 7) BN2 stats over P0+P1
    bn_part<<<dim3(8, 16), 256, 0, stream>>>(P0, P1, 64, 512, bnp);
    bn_fin<<<2, 256, 0, stream>>>(bnp, 16, 512, 1.0f / 1024.f, g2, b2, s2, t2);

    // 8) h3 = relu(bn2(P0+P1)) -> fp16
    cvt_bnrelu<<<512, 256, 0, stream>>>(P0, P1, s2, t2, h3h);

    // 9) GEMM3: d_out = h3 @ W3^T  (1024x256, K=512)
    gemm_f16<<<dim3(4, 16, 1), 256, 0, stream>>>(h3h, w3h, (float*)d_out, 256, 512, 8, 0);
}

// Round 7
// 152.940 us; speedup vs baseline: 9.3642x; 1.1462x over previous
//
#include <hip/hip_runtime.h>
#include <math.h>

#define SEQL 2048
#define BATCH 1024
#define CHUNK 128
#define NCH 16

typedef _Float16 f16x8 __attribute__((ext_vector_type(8)));
typedef _Float16 f16x4 __attribute__((ext_vector_type(4)));
typedef _Float16 h2 __attribute__((ext_vector_type(2)));
typedef float f32x4 __attribute__((ext_vector_type(4)));

// ---------------------------------------------------------------------------
// fp16 pack/unpack helpers (RNE via v_cvt_f16_f32)
// ---------------------------------------------------------------------------
__device__ inline unsigned short f2h(float f) {
    _Float16 h = (_Float16)f;
    return *reinterpret_cast<unsigned short*>(&h);
}
__device__ inline float packh2(float a, float b) {
    return __uint_as_float((unsigned)f2h(a) | ((unsigned)f2h(b) << 16));
}
// extract fp16 at bit offset sh (0 or 16) from a float-carried pack -> fp32
__device__ inline float hext(float packed, int sh) {
    const unsigned short s = (unsigned short)(__float_as_uint(packed) >> sh);
    _Float16 h = *reinterpret_cast<const _Float16*>(&s);
    return (float)h;
}

__device__ inline void gl2lds16(const void* g, void* l) {
    __builtin_amdgcn_global_load_lds(
        (const __attribute__((address_space(1))) unsigned int*)g,
        (__attribute__((address_space(3))) unsigned int*)l, 16, 0, 0);
}

// DPP cross-lane add: v += dpp_perm(v).
template<int CTRL>
__device__ inline float dppadd(float v) {
    const int p = __builtin_amdgcn_update_dpp(0, __float_as_int(v), CTRL, 0xF, 0xF, true);
    return v + __int_as_float(p);
}

// ---------------------------------------------------------------------------
// Merged fp32->fp16 convert for x (1024 rows, K 1775->1792 zero-pad) and
// W1 (2048 rows, same K/Kp).
// ---------------------------------------------------------------------------
__global__ __launch_bounds__(256) void cvt_xw1(
    const float* __restrict__ x, const float* __restrict__ W1,
    _Float16* __restrict__ xh, _Float16* __restrict__ w1h)
{
    const int bid = blockIdx.x;
    const float* src;
    _Float16* dst;
    if (bid < 1024) { src = x + (size_t)bid * 1775;          dst = xh  + (size_t)bid * 1792; }
    else            { src = W1 + (size_t)(bid - 1024) * 1775; dst = w1h + (size_t)(bid - 1024) * 1792; }
    f16x4* dst4 = reinterpret_cast<f16x4*>(dst);
    for (int i = threadIdx.x; i < 448; i += 256) {
        const int k = i * 4;
        float4 v = {0.f, 0.f, 0.f, 0.f};
        if (k + 3 < 1775) v = *reinterpret_cast<const float4*>(&src[k]);
        else {
            if (k     < 1775) v.x = src[k];
            if (k + 1 < 1775) v.y = src[k + 1];
            if (k + 2 < 1775) v.z = src[k + 2];
        }
        f16x4 o; o[0] = (_Float16)v.x; o[1] = (_Float16)v.y; o[2] = (_Float16)v.z; o[3] = (_Float16)v.w;
        dst4[i] = o;
    }
}

// Merged convert for W2 (512 rows, K=2048) and W3 (256 rows, K=512).
__global__ __launch_bounds__(256) void cvt_w23(
    const float* __restrict__ W2, const float* __restrict__ W3,
    _Float16* __restrict__ w2h, _Float16* __restrict__ w3h)
{
    const int bid = blockIdx.x;
    const float* src;
    _Float16* dst;
    int nvec;
    if (bid < 512) { src = W2 + (size_t)bid * 2048;        dst = w2h + (size_t)bid * 2048; nvec = 512; }
    else           { src = W3 + (size_t)(bid - 512) * 512; dst = w3h + (size_t)(bid - 512) * 512; nvec = 128; }
    f16x4* dst4 = reinterpret_cast<f16x4*>(dst);
    for (int i = threadIdx.x; i < nvec; i += 256) {
        const float4 v = reinterpret_cast<const float4*>(src)[i];
        f16x4 o; o[0] = (_Float16)v.x; o[1] = (_Float16)v.y; o[2] = (_Float16)v.z; o[3] = (_Float16)v.w;
        dst4[i] = o;
    }
}

// h3 = relu(bn2(P0+P1)) -> fp16.  2 rows per block, K=512.
__global__ __launch_bounds__(256) void cvt_bnrelu(
    const float* __restrict__ P0, const float* __restrict__ P1,
    const float* __restrict__ sc, const float* __restrict__ tc,
    _Float16* __restrict__ h3)
{
    const int row = blockIdx.x * 2 + (threadIdx.x >> 7);
    const int i = threadIdx.x & 127;
    const float4 p0 = reinterpret_cast<const float4*>(P0 + (size_t)row * 512)[i];
    const float4 p1 = reinterpret_cast<const float4*>(P1 + (size_t)row * 512)[i];
    const float4 sv = reinterpret_cast<const float4*>(sc)[i];
    const float4 tv = reinterpret_cast<const float4*>(tc)[i];
    f16x4 o;
    o[0] = (_Float16)fmaxf(fmaf(sv.x, p0.x + p1.x, tv.x), 0.f);
    o[1] = (_Float16)fmaxf(fmaf(sv.y, p0.y + p1.y, tv.y), 0.f);
    o[2] = (_Float16)fmaxf(fmaf(sv.z, p0.z + p1.z, tv.z), 0.f);
    o[3] = (_Float16)fmaxf(fmaf(sv.w, p0.w + p1.w, tv.w), 0.f);
    reinterpret_cast<f16x4*>(h3 + (size_t)row * 512)[i] = o;
}

// ---------------------------------------------------------------------------
// fp16 MFMA GEMM (NT): C[m][n] = sum_k A[m][k]*B[n][k]. 64x64 tile, BK=64,
// 4 waves, 16x16x32_f16 MFMA, global_load_lds staging, XOR slot swizzle
// (slot ^= row&7) on BOTH the pre-swizzled global source and the fragment
// read. Optional split-K over blockIdx.z.
// ---------------------------------------------------------------------------
__global__ __launch_bounds__(256) void gemm_f16(
    const _Float16* __restrict__ A, const _Float16* __restrict__ B,
    float* __restrict__ C, int ldc, int Kp, int ksteps, size_t coff)
{
    __shared__ __attribute__((aligned(16))) _Float16 sA[64 * 64];  // 8 KB
    __shared__ __attribute__((aligned(16))) _Float16 sB[64 * 64];  // 8 KB

    const int tid = threadIdx.x;
    const int wave = tid >> 6;
    const int lane = tid & 63;
    const int m0 = blockIdx.y * 64;
    const int n0 = blockIdx.x * 64;
    C += (size_t)blockIdx.z * coff;

    const int srow = tid >> 3;          // 0..31
    const int pslot = tid & 7;
    const int gslot = pslot ^ (srow & 7);
    const size_t gk0 = (size_t)blockIdx.z * ksteps * 64 + gslot * 8;
    const _Float16* gA0 = A + (size_t)(m0 + srow) * Kp + gk0;
    const _Float16* gA1 = A + (size_t)(m0 + 32 + srow) * Kp + gk0;
    const _Float16* gB0 = B + (size_t)(n0 + srow) * Kp + gk0;
    const _Float16* gB1 = B + (size_t)(n0 + 32 + srow) * Kp + gk0;
    const int wdst = wave * 512;

    const int wr = wave >> 1, wc = wave & 1;
    const int li = lane & 15, gq = lane >> 4;
    const int p0s = (gq    ) ^ (li & 7);
    const int p1s = (gq + 4) ^ (li & 7);

    f32x4 acc[2][2];
    #pragma unroll
    for (int i = 0; i < 2; ++i)
        #pragma unroll
        for (int j = 0; j < 2; ++j)
            #pragma unroll
            for (int v = 0; v < 4; ++v) acc[i][j][v] = 0.f;

    for (int kt = 0; kt < ksteps; ++kt) {
        const size_t go = (size_t)kt * 64;
        gl2lds16(gA0 + go, &sA[wdst]);
        gl2lds16(gA1 + go, &sA[2048 + wdst]);
        gl2lds16(gB0 + go, &sB[wdst]);
        gl2lds16(gB1 + go, &sB[2048 + wdst]);
        __syncthreads();

        f16x8 af[2][2], bg[2][2];
        #pragma unroll
        for (int mi = 0; mi < 2; ++mi) {
            const int rb = (wr * 32 + mi * 16 + li) * 64;
            af[mi][0] = *(const f16x8*)&sA[rb + p0s * 8];
            af[mi][1] = *(const f16x8*)&sA[rb + p1s * 8];
        }
        #pragma unroll
        for (int ni = 0; ni < 2; ++ni) {
            const int rb = (wc * 32 + ni * 16 + li) * 64;
            bg[ni][0] = *(const f16x8*)&sB[rb + p0s * 8];
            bg[ni][1] = *(const f16x8*)&sB[rb + p1s * 8];
        }
        #pragma unroll
        for (int mi = 0; mi < 2; ++mi)
            #pragma unroll
            for (int ni = 0; ni < 2; ++ni) {
                acc[mi][ni] = __builtin_amdgcn_mfma_f32_16x16x32_f16(af[mi][0], bg[ni][0], acc[mi][ni], 0, 0, 0);
                acc[mi][ni] = __builtin_amdgcn_mfma_f32_16x16x32_f16(af[mi][1], bg[ni][1], acc[mi][ni], 0, 0, 0);
            }
        __syncthreads();
    }

    #pragma unroll
    for (int mi = 0; mi < 2; ++mi)
        #pragma unroll
        for (int ni = 0; ni < 2; ++ni) {
            const int col = n0 + wc * 32 + ni * 16 + li;
            #pragma unroll
            for (int i = 0; i < 4; ++i) {
                const int row = m0 + wr * 32 + mi * 16 + gq * 4 + i;
                C[(size_t)row * ldc + col] = acc[mi][ni][i];
            }
        }
}

// ---------------------------------------------------------------------------
// Two-pass batchnorm stats.
// ---------------------------------------------------------------------------
__global__ __launch_bounds__(256) void bn_part(
    const float* __restrict__ X, const float* __restrict__ X2,
    int rows_per, int ld, float* __restrict__ part)
{
    __shared__ float rs[4][64], rq[4][64];
    const int tid = threadIdx.x;
    const int c = tid & 63, rg4 = tid >> 6;
    const int col = blockIdx.x * 64 + c;
    const int r0 = blockIdx.y * rows_per;
    float sum = 0.f, sq = 0.f;
    for (int r = rg4; r < rows_per; r += 4) {
        const size_t idx = (size_t)(r0 + r) * ld + col;
        float v = X[idx];
        if (X2) v += X2[idx];
        sum += v; sq += v * v;
    }
    rs[rg4][c] = sum; rq[rg4][c] = sq;
    __syncthreads();
    if (rg4 == 0) {
        sum = rs[0][c] + rs[1][c] + rs[2][c] + rs[3][c];
        sq  = rq[0][c] + rq[1][c] + rq[2][c] + rq[3][c];
        part[((size_t)blockIdx.y * 2    ) * ld + col] = sum;
        part[((size_t)blockIdx.y * 2 + 1) * ld + col] = sq;
    }
}

__global__ __launch_bounds__(256) void bn_fin(
    const float* __restrict__ part, int RG, int ld, float inv_rows,
    const float* __restrict__ g, const float* __restrict__ b,
    float* __restrict__ s, float* __restrict__ t)
{
    const int col = blockIdx.x * 256 + threadIdx.x;
    if (col >= ld) return;
    float sum = 0.f, sq = 0.f;
    for (int z = 0; z < RG; ++z) {
        sum += part[((size_t)z * 2    ) * ld + col];
        sq  += part[((size_t)z * 2 + 1) * ld + col];
    }
    const float mean = sum * inv_rows;
    const float var = fmaxf(sq * inv_rows - mean * mean, 0.f);
    const float rstd = 1.0f / sqrtf(var + 1e-5f);
    const float sv = g[col] * rstd;
    s[col] = sv;
    t[col] = b[col] - mean * sv;
}

// ---------------------------------------------------------------------------
// Chunked-parallel mamba scan, v6:
//  - 512 threads, 16 chunks of 128: half the serial path, 4 blocks/CU with
//    8 waves each -> 32 waves/CU ceiling.
//  - v_dot2_f32_f16 (fdot2) computes Bn/Cn from the packed xs half2 in one
//    instruction; wxB/wxC held as fp16 pairs.
//  - dA = exp2(dte * (Aen*log2e)): one mul + v_exp per step.
// ---------------------------------------------------------------------------
__global__ __launch_bounds__(512, 8) void mamba_scan6(
    const float* __restrict__ Y, _Float16* __restrict__ a2,
    const float* __restrict__ s1, const float* __restrict__ t1,
    const float* __restrict__ Win, const float* __restrict__ convw,
    const float* __restrict__ convb, const float* __restrict__ Wx,
    const float* __restrict__ Wdt, const float* __restrict__ bdt,
    const float* __restrict__ Alog, const float* __restrict__ Dp,
    const float* __restrict__ Wout)
{
    __shared__ __align__(16) float4 pk[SEQL];   // 32 KB (dt0,dt1,xs h2,gate h2)
    __shared__ float Ps[NCH][32];
    __shared__ float Ss[NCH][32];
    __shared__ float Hin[NCH][32];

    const int tid = threadIdx.x;
    const int row = blockIdx.x;
    const float* yrow = Y + (size_t)row * SEQL;
    _Float16* a2row = a2 + (size_t)row * SEQL;

    // ---- phase A': steps [4*tid, 4*tid+4) ---------------------------------
    {
        const int l0 = tid * 4;
        float4 ym = {0.f,0.f,0.f,0.f}, sm = {0.f,0.f,0.f,0.f}, tm = {0.f,0.f,0.f,0.f};
        if (tid > 0) {
            ym = *reinterpret_cast<const float4*>(&yrow[l0 - 4]);
            sm = *reinterpret_cast<const float4*>(&s1[l0 - 4]);
            tm = *reinterpret_cast<const float4*>(&t1[l0 - 4]);
        }
        const float4 y0 = *reinterpret_cast<const float4*>(&yrow[l0]);
        const float4 s0 = *reinterpret_cast<const float4*>(&s1[l0]);
        const float4 t0 = *reinterpret_cast<const float4*>(&t1[l0]);

        float ua[8];
        ua[0] = fmaf(sm.x, ym.x, tm.x);
        ua[1] = fmaf(sm.y, ym.y, tm.y);
        ua[2] = fmaf(sm.z, ym.z, tm.z);
        ua[3] = fmaf(sm.w, ym.w, tm.w);
        ua[4] = fmaf(s0.x, y0.x, t0.x);
        ua[5] = fmaf(s0.y, y0.y, t0.y);
        ua[6] = fmaf(s0.z, y0.z, t0.z);
        ua[7] = fmaf(s0.w, y0.w, t0.w);

        const float wi0 = Win[0], wi1 = Win[1];
        const float wz0 = Win[2], wz1 = Win[3];
        const float wo0 = Wout[0], wo1 = Wout[1];
        const float cw00 = convw[0], cw01 = convw[1], cw02 = convw[2], cw03 = convw[3];
        const float cw10 = convw[4], cw11 = convw[5], cw12 = convw[6], cw13 = convw[7];
        const float cb0 = convb[0], cb1 = convb[1];
        const float wx00 = Wx[0], wx01 = Wx[1];
        const float wdt0 = Wdt[0], wdt1 = Wdt[1];
        const float bdt0 = bdt[0], bdt1 = bdt[1];

        #pragma unroll
        for (int j = 0; j < 4; ++j) {
            const float u0 = ua[j + 4], um1 = ua[j + 3], um2 = ua[j + 2], um3 = ua[j + 1];
            const float c0 = fmaf(wi0, cw00 * um3 + cw01 * um2 + cw02 * um1 + cw03 * u0, cb0);
            const float c1 = fmaf(wi1, cw10 * um3 + cw11 * um2 + cw12 * um1 + cw13 * u0, cb1);
            const float xs0 = c0 / (1.f + __expf(-c0));
            const float xs1 = c1 / (1.f + __expf(-c1));
            const float d0 = xs0 * wx00 + xs1 * wx01;
            const float dt0 = __logf(1.f + __expf(fmaf(d0, wdt0, bdt0)));
            const float dt1 = __logf(1.f + __expf(fmaf(d0, wdt1, bdt1)));
            const float z0 = u0 * wz0, z1 = u0 * wz1;
            const float g0 = (z0 / (1.f + __expf(-z0))) * wo0;
            const float g1 = (z1 / (1.f + __expf(-z1))) * wo1;
            float4 rec;
            rec.x = dt0; rec.y = dt1;
            rec.z = packh2(xs0, xs1);
            rec.w = packh2(g0, g1);
            pk[l0 + j] = rec;
        }
    }
    __syncthreads();

    // ---- lane decomposition ----------------------------------------------
    const int c  = tid >> 5;       // chunk = half-wave, 0..15
    const int l5 = tid & 31;
    const int e  = l5 >> 4;
    const int n  = l5 & 15;
    const int base = c * CHUNK;
    const int esh = e * 16;

    const float Aen2 = -__expf(Alog[e * 16 + n]) * 1.44269504f;  // * log2(e)
    h2 wxB2, wxC2;
    wxB2[0] = (_Float16)Wx[(1 + n) * 2 + 0];
    wxB2[1] = (_Float16)Wx[(1 + n) * 2 + 1];
    wxC2[0] = (_Float16)Wx[(17 + n) * 2 + 0];
    wxC2[1] = (_Float16)Wx[(17 + n) * 2 + 1];

    // ---- phase A'': local scan, h_in = 0 ---------------------------------
    {
        float h = 0.f, p = 1.f;
        for (int i0 = 0; i0 < CHUNK; i0 += 8) {
            #pragma unroll
            for (int j = 0; j < 8; ++j) {
                const float4 v = pk[base + i0 + j];
                const float dte = e ? v.y : v.x;
                const h2 xs2 = __builtin_bit_cast(h2, v.z);
                const float Bn = __builtin_amdgcn_fdot2(xs2, wxB2, 0.f, false);
                const float xe = hext(v.z, esh);
                const float dA = __builtin_amdgcn_exp2f(dte * Aen2);
                h = fmaf(h, dA, dte * xe * Bn);
                p *= dA;
            }
        }
        Ps[c][l5] = p;
        Ss[c][l5] = h;
    }
    __syncthreads();

    // ---- phase B: serial chunk combine -----------------------------------
    if (tid < 32) {
        float H = 0.f;
        #pragma unroll
        for (int cc = 0; cc < NCH; ++cc) {
            Hin[cc][tid] = H;
            H = fmaf(Ps[cc][tid], H, Ss[cc][tid]);
        }
    }
    __syncthreads();

    // ---- phase C: seeded re-scan + fp16 output ----------------------------
    {
        const float De16 = Dp[e] * 0.0625f;
        float h = Hin[c][l5];
        for (int i0 = 0; i0 < CHUNK; i0 += 8) {
            #pragma unroll
            for (int j = 0; j < 8; ++j) {
                const int i = i0 + j;
                const float4 v = pk[base + i];
                const float dte = e ? v.y : v.x;
                const h2 xs2 = __builtin_bit_cast(h2, v.z);
                const float Bn = __builtin_amdgcn_fdot2(xs2, wxB2, 0.f, false);
                const float Cn = __builtin_amdgcn_fdot2(xs2, wxC2, 0.f, false);
                const float xe = hext(v.z, esh);
                const float ge = hext(v.w, esh);
                const float dA = __builtin_amdgcn_exp2f(dte * Aen2);
                h = fmaf(h, dA, dte * xe * Bn);
                float q = fmaf(h, Cn, De16 * xe) * ge;
                q = dppadd<0xB1>(q);    // xor1
                q = dppadd<0x4E>(q);    // xor2
                q = dppadd<0x141>(q);   // xor4 (row_half_mirror)
                q = dppadd<0x140>(q);   // xor8 (row_mirror)
                q = dppadd<0x142>(q);   // row_bcast15 -> lanes 16..31
                if (l5 == 16) a2row[base + i] = (_Float16)q;
            }
        }
    }
}

// ---------------------------------------------------------------------------
extern "C" void kernel_launch(void* const* d_in, const int* in_sizes, int n_in,
                              void* d_out, int out_size, void* d_ws, size_t ws_size,
                              hipStream_t stream)
{
    const float* x     = (const float*)d_in[0];
    const float* W1    = (const float*)d_in[1];
    const float* g1    = (const float*)d_in[2];
    const float* b1    = (const float*)d_in[3];
    const float* Win   = (const float*)d_in[4];
    const float* convw = (const float*)d_in[5];
    const float* convb = (const float*)d_in[6];
    const float* Wx    = (const float*)d_in[7];
    const float* Wdt   = (const float*)d_in[8];
    const float* bdt   = (const float*)d_in[9];
    const float* Alog  = (const float*)d_in[10];
    const float* Dp    = (const float*)d_in[11];
    const float* Wout  = (const float*)d_in[12];
    const float* W2    = (const float*)d_in[13];
    const float* g2    = (const float*)d_in[14];
    const float* b2    = (const float*)d_in[15];
    const float* W3    = (const float*)d_in[16];

    unsigned char* base = (unsigned char*)d_ws;
    float* C1 = (float*)(base + 0);                        // 8,388,608 B
    float* P0 = (float*)(base + 8388608);                  // 2,097,152
    float* P1 = (float*)(base + 10485760);                 // 2,097,152
    float* s1 = (float*)(base + 12582912);
    float* t1 = (float*)(base + 12591104);
    float* s2 = (float*)(base + 12599296);
    float* t2 = (float*)(base + 12601344);
    // pool X (8.39 MB): xh (3.67 MB) until GEMM1; then a2 (4.19 MB);
    // bn partials at +4.5 MiB (disjoint from both).
    unsigned char* pX = base + 12603392;
    _Float16* xh = (_Float16*)pX;
    _Float16* a2 = (_Float16*)pX;
    float* bnp = (float*)(pX + 4718592);
    // pool W (14.68 MB): w1h (7.34 MB) until GEMM1; then w2h/w3h/h3h.
    unsigned char* pW = base + 20992000;
    _Float16* w1h = (_Float16*)pW;
    _Float16* w2h = (_Float16*)pW;                         // 2,097,152 B
    _Float16* w3h = (_Float16*)(pW + 2097152);             //   262,144 B
    _Float16* h3h = (_Float16*)(pW + 2359296);             // 1,048,576 B

    // 1) cvt x, W1 -> fp16 (merged)
    cvt_xw1<<<3072, 256, 0, stream>>>(x, W1, xh, w1h);

    // 2) GEMM1: C1 = x @ W1^T   (M=1024, N=2048, Kp=1792, BK=64)
    gemm_f16<<<dim3(32, 16, 1), 256, 0, stream>>>(xh, w1h, C1, 2048, 1792, 28, 0);

    // 3) BN1 stats
    bn_part<<<dim3(32, 8), 256, 0, stream>>>(C1, nullptr, 128, 2048, bnp);
    bn_fin<<<8, 256, 0, stream>>>(bnp, 8, 2048, 1.0f / 1024.f, g1, b1, s1, t1);

    // 4) cvt W2, W3 -> fp16 (merged; w1h region now dead)
    cvt_w23<<<768, 256, 0, stream>>>(W2, W3, w2h, w3h);

    // 5) mamba scan: reads C1, writes a2 (fp16)
    mamba_scan6<<<1024, 512, 0, stream>>>(C1, a2, s1, t1, Win, convw, convb,
                                          Wx, Wdt, bdt, Alog, Dp, Wout);

    // 6) GEMM2 (split-K=2): P0/P1 = a2 @ W2^T  (1024x512, K=2048)
    gemm_f16<<<dim3(8, 16, 2), 256, 0, stream>>>(a2, w2h, P0, 512, 2048, 16,
                                                 (size_t)1024 * 512);

    // 7) BN2 stats over P0+P1
    bn_part<<<dim3(8, 16), 256, 0, stream>>>(P0, P1, 64, 512, bnp);
    bn_fin<<<2, 256, 0, stream>>>(bnp, 16, 512, 1.0f / 1024.f, g2, b2, s2, t2);

    // 8) h3 = relu(bn2(P0+P1)) -> fp16
    cvt_bnrelu<<<512, 256, 0, stream>>>(P0, P1, s2, t2, h3h);

    // 9) GEMM3: d_out = h3 @ W3^T  (1024x256, K=512)
    gemm_f16<<<dim3(4, 16, 1), 256, 0, stream>>>(h3h, w3h, (float*)d_out, 256, 512, 8, 0);
}

// Round 8
// 148.360 us; speedup vs baseline: 9.6533x; 1.0309x over previous
//
#include <hip/hip_runtime.h>
#include <math.h>

#define SEQL 2048
#define BATCH 1024
#define CHUNK 128
#define NCH 16

typedef _Float16 f16x8 __attribute__((ext_vector_type(8)));
typedef _Float16 f16x4 __attribute__((ext_vector_type(4)));
typedef _Float16 h2 __attribute__((ext_vector_type(2)));
typedef float f32x4 __attribute__((ext_vector_type(4)));

// ---------------------------------------------------------------------------
// fp16 pack/unpack helpers
// ---------------------------------------------------------------------------
__device__ inline unsigned short f2h(float f) {
    _Float16 h = (_Float16)f;
    return *reinterpret_cast<unsigned short*>(&h);
}
__device__ inline float packh2(float a, float b) {
    return __uint_as_float((unsigned)f2h(a) | ((unsigned)f2h(b) << 16));
}
// extract fp16 at bit offset sh (0 or 16) from a float-carried pack -> fp32
__device__ inline float hext(float packed, int sh) {
    const unsigned short s = (unsigned short)(__float_as_uint(packed) >> sh);
    _Float16 h = *reinterpret_cast<const _Float16*>(&s);
    return (float)h;
}

__device__ inline void gl2lds16(const void* g, void* l) {
    __builtin_amdgcn_global_load_lds(
        (const __attribute__((address_space(1))) unsigned int*)g,
        (__attribute__((address_space(3))) unsigned int*)l, 16, 0, 0);
}

// DPP cross-lane add: v += dpp_perm(v).
template<int CTRL>
__device__ inline float dppadd(float v) {
    const int p = __builtin_amdgcn_update_dpp(0, __float_as_int(v), CTRL, 0xF, 0xF, true);
    return v + __int_as_float(p);
}

// ---------------------------------------------------------------------------
// Merged fp32->fp16 convert: x (1024 rows, 1775->1792), W1 (2048 rows, same),
// W2 (512 rows, K=2048), W3 (256 rows, K=512).
// ---------------------------------------------------------------------------
__global__ __launch_bounds__(256) void cvt_all(
    const float* __restrict__ x, const float* __restrict__ W1,
    const float* __restrict__ W2, const float* __restrict__ W3,
    _Float16* __restrict__ xh, _Float16* __restrict__ w1h,
    _Float16* __restrict__ w2h, _Float16* __restrict__ w3h)
{
    const int bid = blockIdx.x;
    if (bid < 3072) {
        const float* src; _Float16* dst;
        if (bid < 1024) { src = x + (size_t)bid * 1775;           dst = xh  + (size_t)bid * 1792; }
        else            { src = W1 + (size_t)(bid - 1024) * 1775; dst = w1h + (size_t)(bid - 1024) * 1792; }
        f16x4* dst4 = reinterpret_cast<f16x4*>(dst);
        for (int i = threadIdx.x; i < 448; i += 256) {
            const int k = i * 4;
            float4 v = {0.f, 0.f, 0.f, 0.f};
            if (k + 3 < 1775) v = *reinterpret_cast<const float4*>(&src[k]);
            else {
                if (k     < 1775) v.x = src[k];
                if (k + 1 < 1775) v.y = src[k + 1];
                if (k + 2 < 1775) v.z = src[k + 2];
            }
            f16x4 o; o[0] = (_Float16)v.x; o[1] = (_Float16)v.y; o[2] = (_Float16)v.z; o[3] = (_Float16)v.w;
            dst4[i] = o;
        }
    } else {
        const float* src; _Float16* dst; int nvec;
        if (bid < 3584) { const int r = bid - 3072; src = W2 + (size_t)r * 2048; dst = w2h + (size_t)r * 2048; nvec = 512; }
        else            { const int r = bid - 3584; src = W3 + (size_t)r * 512;  dst = w3h + (size_t)r * 512;  nvec = 128; }
        f16x4* dst4 = reinterpret_cast<f16x4*>(dst);
        for (int i = threadIdx.x; i < nvec; i += 256) {
            const float4 v = reinterpret_cast<const float4*>(src)[i];
            f16x4 o; o[0] = (_Float16)v.x; o[1] = (_Float16)v.y; o[2] = (_Float16)v.z; o[3] = (_Float16)v.w;
            dst4[i] = o;
        }
    }
}

// h3 = relu(bn2(P0+P1)) -> fp16.  2 rows per block, K=512.
__global__ __launch_bounds__(256) void cvt_bnrelu(
    const float* __restrict__ P0, const float* __restrict__ P1,
    const float* __restrict__ sc, const float* __restrict__ tc,
    _Float16* __restrict__ h3)
{
    const int row = blockIdx.x * 2 + (threadIdx.x >> 7);
    const int i = threadIdx.x & 127;
    const float4 p0 = reinterpret_cast<const float4*>(P0 + (size_t)row * 512)[i];
    const float4 p1 = reinterpret_cast<const float4*>(P1 + (size_t)row * 512)[i];
    const float4 sv = reinterpret_cast<const float4*>(sc)[i];
    const float4 tv = reinterpret_cast<const float4*>(tc)[i];
    f16x4 o;
    o[0] = (_Float16)fmaxf(fmaf(sv.x, p0.x + p1.x, tv.x), 0.f);
    o[1] = (_Float16)fmaxf(fmaf(sv.y, p0.y + p1.y, tv.y), 0.f);
    o[2] = (_Float16)fmaxf(fmaf(sv.z, p0.z + p1.z, tv.z), 0.f);
    o[3] = (_Float16)fmaxf(fmaf(sv.w, p0.w + p1.w, tv.w), 0.f);
    reinterpret_cast<f16x4*>(h3 + (size_t)row * 512)[i] = o;
}

// ---------------------------------------------------------------------------
// fp16 MFMA GEMM (NT): C[m][n] = sum_k A[m][k]*B[n][k]. 64x64 tile, BK=64,
// 4 waves, 16x16x32_f16 MFMA, global_load_lds staging, XOR slot swizzle
// (slot ^= row&7) on BOTH the pre-swizzled global source and the fragment
// read. Optional split-K over blockIdx.z.
// If bnp != nullptr: epilogue also writes per-(m-block, wave-half) column
// sum / sumsq partials (deterministic, no atomics) for a following bn_fin.
// ---------------------------------------------------------------------------
__global__ __launch_bounds__(256) void gemm_f16(
    const _Float16* __restrict__ A, const _Float16* __restrict__ B,
    float* __restrict__ C, int ldc, int Kp, int ksteps, size_t coff,
    float* __restrict__ bnp, int bn_ld)
{
    __shared__ __attribute__((aligned(16))) _Float16 sA[64 * 64];  // 8 KB
    __shared__ __attribute__((aligned(16))) _Float16 sB[64 * 64];  // 8 KB

    const int tid = threadIdx.x;
    const int wave = tid >> 6;
    const int lane = tid & 63;
    const int m0 = blockIdx.y * 64;
    const int n0 = blockIdx.x * 64;
    C += (size_t)blockIdx.z * coff;

    const int srow = tid >> 3;          // 0..31
    const int pslot = tid & 7;
    const int gslot = pslot ^ (srow & 7);
    const size_t gk0 = (size_t)blockIdx.z * ksteps * 64 + gslot * 8;
    const _Float16* gA0 = A + (size_t)(m0 + srow) * Kp + gk0;
    const _Float16* gA1 = A + (size_t)(m0 + 32 + srow) * Kp + gk0;
    const _Float16* gB0 = B + (size_t)(n0 + srow) * Kp + gk0;
    const _Float16* gB1 = B + (size_t)(n0 + 32 + srow) * Kp + gk0;
    const int wdst = wave * 512;

    const int wr = wave >> 1, wc = wave & 1;
    const int li = lane & 15, gq = lane >> 4;
    const int p0s = (gq    ) ^ (li & 7);
    const int p1s = (gq + 4) ^ (li & 7);

    f32x4 acc[2][2];
    #pragma unroll
    for (int i = 0; i < 2; ++i)
        #pragma unroll
        for (int j = 0; j < 2; ++j)
            #pragma unroll
            for (int v = 0; v < 4; ++v) acc[i][j][v] = 0.f;

    for (int kt = 0; kt < ksteps; ++kt) {
        const size_t go = (size_t)kt * 64;
        gl2lds16(gA0 + go, &sA[wdst]);
        gl2lds16(gA1 + go, &sA[2048 + wdst]);
        gl2lds16(gB0 + go, &sB[wdst]);
        gl2lds16(gB1 + go, &sB[2048 + wdst]);
        __syncthreads();

        f16x8 af[2][2], bg[2][2];
        #pragma unroll
        for (int mi = 0; mi < 2; ++mi) {
            const int rb = (wr * 32 + mi * 16 + li) * 64;
            af[mi][0] = *(const f16x8*)&sA[rb + p0s * 8];
            af[mi][1] = *(const f16x8*)&sA[rb + p1s * 8];
        }
        #pragma unroll
        for (int ni = 0; ni < 2; ++ni) {
            const int rb = (wc * 32 + ni * 16 + li) * 64;
            bg[ni][0] = *(const f16x8*)&sB[rb + p0s * 8];
            bg[ni][1] = *(const f16x8*)&sB[rb + p1s * 8];
        }
        #pragma unroll
        for (int mi = 0; mi < 2; ++mi)
            #pragma unroll
            for (int ni = 0; ni < 2; ++ni) {
                acc[mi][ni] = __builtin_amdgcn_mfma_f32_16x16x32_f16(af[mi][0], bg[ni][0], acc[mi][ni], 0, 0, 0);
                acc[mi][ni] = __builtin_amdgcn_mfma_f32_16x16x32_f16(af[mi][1], bg[ni][1], acc[mi][ni], 0, 0, 0);
            }
        __syncthreads();
    }

    #pragma unroll
    for (int mi = 0; mi < 2; ++mi)
        #pragma unroll
        for (int ni = 0; ni < 2; ++ni) {
            const int col = n0 + wc * 32 + ni * 16 + li;
            #pragma unroll
            for (int i = 0; i < 4; ++i) {
                const int row = m0 + wr * 32 + mi * 16 + gq * 4 + i;
                C[(size_t)row * ldc + col] = acc[mi][ni][i];
            }
        }

    // ---- optional fused batchnorm partials (sum / sumsq over this block's
    // 64 rows, per column; one partial row-group per (m-block, wr)) --------
    if (bnp) {
        #pragma unroll
        for (int ni = 0; ni < 2; ++ni) {
            float ps = 0.f, pq = 0.f;
            #pragma unroll
            for (int mi = 0; mi < 2; ++mi)
                #pragma unroll
                for (int i = 0; i < 4; ++i) {
                    const float v = acc[mi][ni][i];
                    ps += v; pq += v * v;
                }
            ps += __shfl_xor(ps, 16); ps += __shfl_xor(ps, 32);
            pq += __shfl_xor(pq, 16); pq += __shfl_xor(pq, 32);
            if (gq == 0) {
                const int col = n0 + wc * 32 + ni * 16 + li;
                const int grp = blockIdx.y * 2 + wr;
                bnp[(size_t)(grp * 2    ) * bn_ld + col] = ps;
                bnp[(size_t)(grp * 2 + 1) * bn_ld + col] = pq;
            }
        }
    }
}

// ---------------------------------------------------------------------------
// Two-pass batchnorm stats (pass 1 still used for BN2 over P0+P1).
// ---------------------------------------------------------------------------
__global__ __launch_bounds__(256) void bn_part(
    const float* __restrict__ X, const float* __restrict__ X2,
    int rows_per, int ld, float* __restrict__ part)
{
    __shared__ float rs[4][64], rq[4][64];
    const int tid = threadIdx.x;
    const int c = tid & 63, rg4 = tid >> 6;
    const int col = blockIdx.x * 64 + c;
    const int r0 = blockIdx.y * rows_per;
    float sum = 0.f, sq = 0.f;
    for (int r = rg4; r < rows_per; r += 4) {
        const size_t idx = (size_t)(r0 + r) * ld + col;
        float v = X[idx];
        if (X2) v += X2[idx];
        sum += v; sq += v * v;
    }
    rs[rg4][c] = sum; rq[rg4][c] = sq;
    __syncthreads();
    if (rg4 == 0) {
        sum = rs[0][c] + rs[1][c] + rs[2][c] + rs[3][c];
        sq  = rq[0][c] + rq[1][c] + rq[2][c] + rq[3][c];
        part[((size_t)blockIdx.y * 2    ) * ld + col] = sum;
        part[((size_t)blockIdx.y * 2 + 1) * ld + col] = sq;
    }
}

__global__ __launch_bounds__(256) void bn_fin(
    const float* __restrict__ part, int RG, int ld, float inv_rows,
    const float* __restrict__ g, const float* __restrict__ b,
    float* __restrict__ s, float* __restrict__ t)
{
    const int col = blockIdx.x * 256 + threadIdx.x;
    if (col >= ld) return;
    float sum = 0.f, sq = 0.f;
    for (int z = 0; z < RG; ++z) {
        sum += part[((size_t)z * 2    ) * ld + col];
        sq  += part[((size_t)z * 2 + 1) * ld + col];
    }
    const float mean = sum * inv_rows;
    const float var = fmaxf(sq * inv_rows - mean * mean, 0.f);
    const float rstd = 1.0f / sqrtf(var + 1e-5f);
    const float sv = g[col] * rstd;
    s[col] = sv;
    t[col] = b[col] - mean * sv;
}

// ---------------------------------------------------------------------------
// Chunked-parallel mamba scan, v7:
//  - phase C: 8 outputs batched in regs, packed via v_cvt_pkrtz, one
//    global_store_dwordx4 per 8 steps under a single exec toggle.
//  - gate/De applied post-reduction (xe/ge uniform within each e-group).
// ---------------------------------------------------------------------------
__global__ __launch_bounds__(512, 8) void mamba_scan7(
    const float* __restrict__ Y, _Float16* __restrict__ a2,
    const float* __restrict__ s1, const float* __restrict__ t1,
    const float* __restrict__ Win, const float* __restrict__ convw,
    const float* __restrict__ convb, const float* __restrict__ Wx,
    const float* __restrict__ Wdt, const float* __restrict__ bdt,
    const float* __restrict__ Alog, const float* __restrict__ Dp,
    const float* __restrict__ Wout)
{
    __shared__ __align__(16) float4 pk[SEQL];   // 32 KB (dt0,dt1,xs h2,gate h2)
    __shared__ float Ps[NCH][32];
    __shared__ float Ss[NCH][32];
    __shared__ float Hin[NCH][32];

    const int tid = threadIdx.x;
    const int row = blockIdx.x;
    const float* yrow = Y + (size_t)row * SEQL;
    _Float16* a2row = a2 + (size_t)row * SEQL;

    // ---- phase A': steps [4*tid, 4*tid+4) ---------------------------------
    {
        const int l0 = tid * 4;
        float4 ym = {0.f,0.f,0.f,0.f}, sm = {0.f,0.f,0.f,0.f}, tm = {0.f,0.f,0.f,0.f};
        if (tid > 0) {
            ym = *reinterpret_cast<const float4*>(&yrow[l0 - 4]);
            sm = *reinterpret_cast<const float4*>(&s1[l0 - 4]);
            tm = *reinterpret_cast<const float4*>(&t1[l0 - 4]);
        }
        const float4 y0 = *reinterpret_cast<const float4*>(&yrow[l0]);
        const float4 s0 = *reinterpret_cast<const float4*>(&s1[l0]);
        const float4 t0 = *reinterpret_cast<const float4*>(&t1[l0]);

        float ua[8];
        ua[0] = fmaf(sm.x, ym.x, tm.x);
        ua[1] = fmaf(sm.y, ym.y, tm.y);
        ua[2] = fmaf(sm.z, ym.z, tm.z);
        ua[3] = fmaf(sm.w, ym.w, tm.w);
        ua[4] = fmaf(s0.x, y0.x, t0.x);
        ua[5] = fmaf(s0.y, y0.y, t0.y);
        ua[6] = fmaf(s0.z, y0.z, t0.z);
        ua[7] = fmaf(s0.w, y0.w, t0.w);

        const float wi0 = Win[0], wi1 = Win[1];
        const float wz0 = Win[2], wz1 = Win[3];
        const float wo0 = Wout[0], wo1 = Wout[1];
        const float cw00 = convw[0], cw01 = convw[1], cw02 = convw[2], cw03 = convw[3];
        const float cw10 = convw[4], cw11 = convw[5], cw12 = convw[6], cw13 = convw[7];
        const float cb0 = convb[0], cb1 = convb[1];
        const float wx00 = Wx[0], wx01 = Wx[1];
        const float wdt0 = Wdt[0], wdt1 = Wdt[1];
        const float bdt0 = bdt[0], bdt1 = bdt[1];

        #pragma unroll
        for (int j = 0; j < 4; ++j) {
            const float u0 = ua[j + 4], um1 = ua[j + 3], um2 = ua[j + 2], um3 = ua[j + 1];
            const float c0 = fmaf(wi0, cw00 * um3 + cw01 * um2 + cw02 * um1 + cw03 * u0, cb0);
            const float c1 = fmaf(wi1, cw10 * um3 + cw11 * um2 + cw12 * um1 + cw13 * u0, cb1);
            const float xs0 = c0 / (1.f + __expf(-c0));
            const float xs1 = c1 / (1.f + __expf(-c1));
            const float d0 = xs0 * wx00 + xs1 * wx01;
            const float dt0 = __logf(1.f + __expf(fmaf(d0, wdt0, bdt0)));
            const float dt1 = __logf(1.f + __expf(fmaf(d0, wdt1, bdt1)));
            const float z0 = u0 * wz0, z1 = u0 * wz1;
            const float g0 = (z0 / (1.f + __expf(-z0))) * wo0;
            const float g1 = (z1 / (1.f + __expf(-z1))) * wo1;
            float4 rec;
            rec.x = dt0; rec.y = dt1;
            rec.z = packh2(xs0, xs1);
            rec.w = packh2(g0, g1);
            pk[l0 + j] = rec;
        }
    }
    __syncthreads();

    // ---- lane decomposition ----------------------------------------------
    const int c  = tid >> 5;       // chunk = half-wave, 0..15
    const int l5 = tid & 31;
    const int e  = l5 >> 4;
    const int n  = l5 & 15;
    const int base = c * CHUNK;
    const int esh = e * 16;

    const float Aen2 = -__expf(Alog[e * 16 + n]) * 1.44269504f;  // * log2(e)
    h2 wxB2, wxC2;
    wxB2[0] = (_Float16)Wx[(1 + n) * 2 + 0];
    wxB2[1] = (_Float16)Wx[(1 + n) * 2 + 1];
    wxC2[0] = (_Float16)Wx[(17 + n) * 2 + 0];
    wxC2[1] = (_Float16)Wx[(17 + n) * 2 + 1];

    // ---- phase A'': local scan, h_in = 0 ---------------------------------
    {
        float h = 0.f, p = 1.f;
        for (int i0 = 0; i0 < CHUNK; i0 += 8) {
            #pragma unroll
            for (int j = 0; j < 8; ++j) {
                const float4 v = pk[base + i0 + j];
                const float dte = e ? v.y : v.x;
                const h2 xs2 = __builtin_bit_cast(h2, v.z);
                const float Bn = __builtin_amdgcn_fdot2(xs2, wxB2, 0.f, false);
                const float xe = hext(v.z, esh);
                const float dA = __builtin_amdgcn_exp2f(dte * Aen2);
                h = fmaf(h, dA, dte * xe * Bn);
                p *= dA;
            }
        }
        Ps[c][l5] = p;
        Ss[c][l5] = h;
    }
    __syncthreads();

    // ---- phase B: serial chunk combine -----------------------------------
    if (tid < 32) {
        float H = 0.f;
        #pragma unroll
        for (int cc = 0; cc < NCH; ++cc) {
            Hin[cc][tid] = H;
            H = fmaf(Ps[cc][tid], H, Ss[cc][tid]);
        }
    }
    __syncthreads();

    // ---- phase C: seeded re-scan + batched packed fp16 output -------------
    {
        const float De = Dp[e];
        float h = Hin[c][l5];
        for (int i0 = 0; i0 < CHUNK; i0 += 8) {
            float qs[8];
            #pragma unroll
            for (int j = 0; j < 8; ++j) {
                const float4 v = pk[base + i0 + j];
                const float dte = e ? v.y : v.x;
                const h2 xs2 = __builtin_bit_cast(h2, v.z);
                const float Bn = __builtin_amdgcn_fdot2(xs2, wxB2, 0.f, false);
                const float Cn = __builtin_amdgcn_fdot2(xs2, wxC2, 0.f, false);
                const float xe = hext(v.z, esh);
                const float ge = hext(v.w, esh);
                const float dA = __builtin_amdgcn_exp2f(dte * Aen2);
                h = fmaf(h, dA, dte * xe * Bn);
                float q = h * Cn;
                q = dppadd<0xB1>(q);    // xor1
                q = dppadd<0x4E>(q);    // xor2
                q = dppadd<0x141>(q);   // xor4 (row_half_mirror)
                q = dppadd<0x140>(q);   // xor8 (row_mirror)
                q = fmaf(De, xe, q) * ge;   // per-e finish (uniform in group)
                q = dppadd<0x142>(q);   // row_bcast15 -> lanes 16..31 total
                qs[j] = q;
            }
            if (l5 == 16) {
                float4 st;
                st.x = __builtin_bit_cast(float, __builtin_amdgcn_cvt_pkrtz(qs[0], qs[1]));
                st.y = __builtin_bit_cast(float, __builtin_amdgcn_cvt_pkrtz(qs[2], qs[3]));
                st.z = __builtin_bit_cast(float, __builtin_amdgcn_cvt_pkrtz(qs[4], qs[5]));
                st.w = __builtin_bit_cast(float, __builtin_amdgcn_cvt_pkrtz(qs[6], qs[7]));
                *reinterpret_cast<float4*>(&a2row[base + i0]) = st;
            }
        }
    }
}

// ---------------------------------------------------------------------------
extern "C" void kernel_launch(void* const* d_in, const int* in_sizes, int n_in,
                              void* d_out, int out_size, void* d_ws, size_t ws_size,
                              hipStream_t stream)
{
    const float* x     = (const float*)d_in[0];
    const float* W1    = (const float*)d_in[1];
    const float* g1    = (const float*)d_in[2];
    const float* b1    = (const float*)d_in[3];
    const float* Win   = (const float*)d_in[4];
    const float* convw = (const float*)d_in[5];
    const float* convb = (const float*)d_in[6];
    const float* Wx    = (const float*)d_in[7];
    const float* Wdt   = (const float*)d_in[8];
    const float* bdt   = (const float*)d_in[9];
    const float* Alog  = (const float*)d_in[10];
    const float* Dp    = (const float*)d_in[11];
    const float* Wout  = (const float*)d_in[12];
    const float* W2    = (const float*)d_in[13];
    const float* g2    = (const float*)d_in[14];
    const float* b2    = (const float*)d_in[15];
    const float* W3    = (const float*)d_in[16];

    unsigned char* base = (unsigned char*)d_ws;   // all regions disjoint
    float* C1 = (float*)(base + 0);               //  8,388,608
    float* P0 = (float*)(base + 8388608);         //  2,097,152
    float* P1 = (float*)(base + 10485760);        //  2,097,152
    float* s1 = (float*)(base + 12582912);        //  8 KB
    float* t1 = (float*)(base + 12591104);        //  8 KB
    float* s2 = (float*)(base + 12599296);        //  2 KB
    float* t2 = (float*)(base + 12601344);        //  2 KB
    float* bnp = (float*)(base + 12615680);       //  524,288 (32 grp x 2 x 2048)
    _Float16* a2  = (_Float16*)(base + 13172736); //  4,194,304
    _Float16* xh  = (_Float16*)(base + 17367040); //  3,670,016
    _Float16* w1h = (_Float16*)(base + 21037056); //  7,340,032
    _Float16* w2h = (_Float16*)(base + 28377088); //  2,097,152
    _Float16* w3h = (_Float16*)(base + 30474240); //    262,144
    _Float16* h3h = (_Float16*)(base + 30736384); //  1,048,576  (end ~31.8 MB)

    // 1) all fp32->fp16 conversions in one grid-filling dispatch
    cvt_all<<<3840, 256, 0, stream>>>(x, W1, W2, W3, xh, w1h, w2h, w3h);

    // 2) GEMM1: C1 = x @ W1^T ; fused BN1 partials into epilogue
    gemm_f16<<<dim3(32, 16, 1), 256, 0, stream>>>(
        xh, w1h, C1, 2048, 1792, 28, 0, bnp, 2048);

    // 3) BN1 finalize (32 partial groups)
    bn_fin<<<8, 256, 0, stream>>>(bnp, 32, 2048, 1.0f / 1024.f, g1, b1, s1, t1);

    // 4) mamba scan: reads C1, writes a2 (fp16)
    mamba_scan7<<<1024, 512, 0, stream>>>(C1, a2, s1, t1, Win, convw, convb,
                                          Wx, Wdt, bdt, Alog, Dp, Wout);

    // 5) GEMM2 (split-K=2): P0/P1 = a2 @ W2^T  (1024x512, K=2048)
    gemm_f16<<<dim3(8, 16, 2), 256, 0, stream>>>(
        a2, w2h, P0, 512, 2048, 16, (size_t)1024 * 512, nullptr, 0);

    // 6) BN2 stats over P0+P1 (split-K partials must be summed before sq)
    bn_part<<<dim3(8, 16), 256, 0, stream>>>(P0, P1, 64, 512, bnp);
    bn_fin<<<2, 256, 0, stream>>>(bnp, 16, 512, 1.0f / 1024.f, g2, b2, s2, t2);

    // 7) h3 = relu(bn2(P0+P1)) -> fp16
    cvt_bnrelu<<<512, 256, 0, stream>>>(P0, P1, s2, t2, h3h);

    // 8) GEMM3: d_out = h3 @ W3^T  (1024x256, K=512)
    gemm_f16<<<dim3(4, 16, 1), 256, 0, stream>>>(
        h3h, w3h, (float*)d_out, 256, 512, 8, 0, nullptr, 0);
}

// Round 9
// 127.322 us; speedup vs baseline: 11.2484x; 1.1652x over previous
//
#include <hip/hip_runtime.h>
#include <math.h>

#define SEQL 2048
#define BATCH 1024
#define CHUNK 64
#define NCH 32

typedef _Float16 f16x8 __attribute__((ext_vector_type(8)));
typedef _Float16 f16x4 __attribute__((ext_vector_type(4)));
typedef _Float16 h2 __attribute__((ext_vector_type(2)));
typedef float f32x4 __attribute__((ext_vector_type(4)));

// ---------------------------------------------------------------------------
// fp16 pack/unpack helpers
// ---------------------------------------------------------------------------
__device__ inline unsigned short f2h(float f) {
    _Float16 h = (_Float16)f;
    return *reinterpret_cast<unsigned short*>(&h);
}
__device__ inline float packh2(float a, float b) {
    return __uint_as_float((unsigned)f2h(a) | ((unsigned)f2h(b) << 16));
}
// extract fp16 at bit offset sh (0 or 16) from a float-carried pack -> fp32
__device__ inline float hext(float packed, int sh) {
    const unsigned short s = (unsigned short)(__float_as_uint(packed) >> sh);
    _Float16 h = *reinterpret_cast<const _Float16*>(&s);
    return (float)h;
}

__device__ inline void gl2lds16(const void* g, void* l) {
    __builtin_amdgcn_global_load_lds(
        (const __attribute__((address_space(1))) unsigned int*)g,
        (__attribute__((address_space(3))) unsigned int*)l, 16, 0, 0);
}

// DPP cross-lane add: v += dpp_perm(v).
template<int CTRL>
__device__ inline float dppadd(float v) {
    const int p = __builtin_amdgcn_update_dpp(0, __float_as_int(v), CTRL, 0xF, 0xF, true);
    return v + __int_as_float(p);
}

// ---------------------------------------------------------------------------
// Merged fp32->fp16 convert: x (1024 rows, 1775->1792), W1 (2048 rows, same),
// W2 (512 rows, K=2048), W3 (256 rows, K=512).
// ---------------------------------------------------------------------------
__global__ __launch_bounds__(256) void cvt_all(
    const float* __restrict__ x, const float* __restrict__ W1,
    const float* __restrict__ W2, const float* __restrict__ W3,
    _Float16* __restrict__ xh, _Float16* __restrict__ w1h,
    _Float16* __restrict__ w2h, _Float16* __restrict__ w3h)
{
    const int bid = blockIdx.x;
    if (bid < 3072) {
        const float* src; _Float16* dst;
        if (bid < 1024) { src = x + (size_t)bid * 1775;           dst = xh  + (size_t)bid * 1792; }
        else            { src = W1 + (size_t)(bid - 1024) * 1775; dst = w1h + (size_t)(bid - 1024) * 1792; }
        f16x4* dst4 = reinterpret_cast<f16x4*>(dst);
        for (int i = threadIdx.x; i < 448; i += 256) {
            const int k = i * 4;
            float4 v = {0.f, 0.f, 0.f, 0.f};
            if (k + 3 < 1775) v = *reinterpret_cast<const float4*>(&src[k]);
            else {
                if (k     < 1775) v.x = src[k];
                if (k + 1 < 1775) v.y = src[k + 1];
                if (k + 2 < 1775) v.z = src[k + 2];
            }
            f16x4 o; o[0] = (_Float16)v.x; o[1] = (_Float16)v.y; o[2] = (_Float16)v.z; o[3] = (_Float16)v.w;
            dst4[i] = o;
        }
    } else {
        const float* src; _Float16* dst; int nvec;
        if (bid < 3584) { const int r = bid - 3072; src = W2 + (size_t)r * 2048; dst = w2h + (size_t)r * 2048; nvec = 512; }
        else            { const int r = bid - 3584; src = W3 + (size_t)r * 512;  dst = w3h + (size_t)r * 512;  nvec = 128; }
        f16x4* dst4 = reinterpret_cast<f16x4*>(dst);
        for (int i = threadIdx.x; i < nvec; i += 256) {
            const float4 v = reinterpret_cast<const float4*>(src)[i];
            f16x4 o; o[0] = (_Float16)v.x; o[1] = (_Float16)v.y; o[2] = (_Float16)v.z; o[3] = (_Float16)v.w;
            dst4[i] = o;
        }
    }
}

// h3 = relu(bn2(P0+P1)) -> fp16.  2 rows per block, K=512.
__global__ __launch_bounds__(256) void cvt_bnrelu(
    const float* __restrict__ P0, const float* __restrict__ P1,
    const float* __restrict__ sc, const float* __restrict__ tc,
    _Float16* __restrict__ h3)
{
    const int row = blockIdx.x * 2 + (threadIdx.x >> 7);
    const int i = threadIdx.x & 127;
    const float4 p0 = reinterpret_cast<const float4*>(P0 + (size_t)row * 512)[i];
    const float4 p1 = reinterpret_cast<const float4*>(P1 + (size_t)row * 512)[i];
    const float4 sv = reinterpret_cast<const float4*>(sc)[i];
    const float4 tv = reinterpret_cast<const float4*>(tc)[i];
    f16x4 o;
    o[0] = (_Float16)fmaxf(fmaf(sv.x, p0.x + p1.x, tv.x), 0.f);
    o[1] = (_Float16)fmaxf(fmaf(sv.y, p0.y + p1.y, tv.y), 0.f);
    o[2] = (_Float16)fmaxf(fmaf(sv.z, p0.z + p1.z, tv.z), 0.f);
    o[3] = (_Float16)fmaxf(fmaf(sv.w, p0.w + p1.w, tv.w), 0.f);
    reinterpret_cast<f16x4*>(h3 + (size_t)row * 512)[i] = o;
}

// ---------------------------------------------------------------------------
// fp16 MFMA GEMM (NT): C[m][n] = sum_k A[m][k]*B[n][k]. 64x64 tile, BK=64,
// 4 waves, 16x16x32_f16 MFMA, global_load_lds staging, XOR slot swizzle
// (slot ^= row&7) on BOTH the pre-swizzled global source and the fragment
// read. Optional split-K over blockIdx.z.
// If bnp != nullptr: epilogue also writes per-(m-block, wave-half) column
// sum / sumsq partials (deterministic, no atomics) for a following bn_fin.
// ---------------------------------------------------------------------------
__global__ __launch_bounds__(256) void gemm_f16(
    const _Float16* __restrict__ A, const _Float16* __restrict__ B,
    float* __restrict__ C, int ldc, int Kp, int ksteps, size_t coff,
    float* __restrict__ bnp, int bn_ld)
{
    __shared__ __attribute__((aligned(16))) _Float16 sA[64 * 64];  // 8 KB
    __shared__ __attribute__((aligned(16))) _Float16 sB[64 * 64];  // 8 KB

    const int tid = threadIdx.x;
    const int wave = tid >> 6;
    const int lane = tid & 63;
    const int m0 = blockIdx.y * 64;
    const int n0 = blockIdx.x * 64;
    C += (size_t)blockIdx.z * coff;

    const int srow = tid >> 3;          // 0..31
    const int pslot = tid & 7;
    const int gslot = pslot ^ (srow & 7);
    const size_t gk0 = (size_t)blockIdx.z * ksteps * 64 + gslot * 8;
    const _Float16* gA0 = A + (size_t)(m0 + srow) * Kp + gk0;
    const _Float16* gA1 = A + (size_t)(m0 + 32 + srow) * Kp + gk0;
    const _Float16* gB0 = B + (size_t)(n0 + srow) * Kp + gk0;
    const _Float16* gB1 = B + (size_t)(n0 + 32 + srow) * Kp + gk0;
    const int wdst = wave * 512;

    const int wr = wave >> 1, wc = wave & 1;
    const int li = lane & 15, gq = lane >> 4;
    const int p0s = (gq    ) ^ (li & 7);
    const int p1s = (gq + 4) ^ (li & 7);

    f32x4 acc[2][2];
    #pragma unroll
    for (int i = 0; i < 2; ++i)
        #pragma unroll
        for (int j = 0; j < 2; ++j)
            #pragma unroll
            for (int v = 0; v < 4; ++v) acc[i][j][v] = 0.f;

    for (int kt = 0; kt < ksteps; ++kt) {
        const size_t go = (size_t)kt * 64;
        gl2lds16(gA0 + go, &sA[wdst]);
        gl2lds16(gA1 + go, &sA[2048 + wdst]);
        gl2lds16(gB0 + go, &sB[wdst]);
        gl2lds16(gB1 + go, &sB[2048 + wdst]);
        __syncthreads();

        f16x8 af[2][2], bg[2][2];
        #pragma unroll
        for (int mi = 0; mi < 2; ++mi) {
            const int rb = (wr * 32 + mi * 16 + li) * 64;
            af[mi][0] = *(const f16x8*)&sA[rb + p0s * 8];
            af[mi][1] = *(const f16x8*)&sA[rb + p1s * 8];
        }
        #pragma unroll
        for (int ni = 0; ni < 2; ++ni) {
            const int rb = (wc * 32 + ni * 16 + li) * 64;
            bg[ni][0] = *(const f16x8*)&sB[rb + p0s * 8];
            bg[ni][1] = *(const f16x8*)&sB[rb + p1s * 8];
        }
        #pragma unroll
        for (int mi = 0; mi < 2; ++mi)
            #pragma unroll
            for (int ni = 0; ni < 2; ++ni) {
                acc[mi][ni] = __builtin_amdgcn_mfma_f32_16x16x32_f16(af[mi][0], bg[ni][0], acc[mi][ni], 0, 0, 0);
                acc[mi][ni] = __builtin_amdgcn_mfma_f32_16x16x32_f16(af[mi][1], bg[ni][1], acc[mi][ni], 0, 0, 0);
            }
        __syncthreads();
    }

    #pragma unroll
    for (int mi = 0; mi < 2; ++mi)
        #pragma unroll
        for (int ni = 0; ni < 2; ++ni) {
            const int col = n0 + wc * 32 + ni * 16 + li;
            #pragma unroll
            for (int i = 0; i < 4; ++i) {
                const int row = m0 + wr * 32 + mi * 16 + gq * 4 + i;
                C[(size_t)row * ldc + col] = acc[mi][ni][i];
            }
        }

    // ---- optional fused batchnorm partials -------------------------------
    if (bnp) {
        #pragma unroll
        for (int ni = 0; ni < 2; ++ni) {
            float ps = 0.f, pq = 0.f;
            #pragma unroll
            for (int mi = 0; mi < 2; ++mi)
                #pragma unroll
                for (int i = 0; i < 4; ++i) {
                    const float v = acc[mi][ni][i];
                    ps += v; pq += v * v;
                }
            ps += __shfl_xor(ps, 16); ps += __shfl_xor(ps, 32);
            pq += __shfl_xor(pq, 16); pq += __shfl_xor(pq, 32);
            if (gq == 0) {
                const int col = n0 + wc * 32 + ni * 16 + li;
                const int grp = blockIdx.y * 2 + wr;
                bnp[(size_t)(grp * 2    ) * bn_ld + col] = ps;
                bnp[(size_t)(grp * 2 + 1) * bn_ld + col] = pq;
            }
        }
    }
}

// ---------------------------------------------------------------------------
// Two-pass batchnorm stats (pass 1 used for BN2 over P0+P1).
// ---------------------------------------------------------------------------
__global__ __launch_bounds__(256) void bn_part(
    const float* __restrict__ X, const float* __restrict__ X2,
    int rows_per, int ld, float* __restrict__ part)
{
    __shared__ float rs[4][64], rq[4][64];
    const int tid = threadIdx.x;
    const int c = tid & 63, rg4 = tid >> 6;
    const int col = blockIdx.x * 64 + c;
    const int r0 = blockIdx.y * rows_per;
    float sum = 0.f, sq = 0.f;
    for (int r = rg4; r < rows_per; r += 4) {
        const size_t idx = (size_t)(r0 + r) * ld + col;
        float v = X[idx];
        if (X2) v += X2[idx];
        sum += v; sq += v * v;
    }
    rs[rg4][c] = sum; rq[rg4][c] = sq;
    __syncthreads();
    if (rg4 == 0) {
        sum = rs[0][c] + rs[1][c] + rs[2][c] + rs[3][c];
        sq  = rq[0][c] + rq[1][c] + rq[2][c] + rq[3][c];
        part[((size_t)blockIdx.y * 2    ) * ld + col] = sum;
        part[((size_t)blockIdx.y * 2 + 1) * ld + col] = sq;
    }
}

__global__ __launch_bounds__(256) void bn_fin(
    const float* __restrict__ part, int RG, int ld, float inv_rows,
    const float* __restrict__ g, const float* __restrict__ b,
    float* __restrict__ s, float* __restrict__ t)
{
    const int col = blockIdx.x * 256 + threadIdx.x;
    if (col >= ld) return;
    float sum = 0.f, sq = 0.f;
    for (int z = 0; z < RG; ++z) {
        sum += part[((size_t)z * 2    ) * ld + col];
        sq  += part[((size_t)z * 2 + 1) * ld + col];
    }
    const float mean = sum * inv_rows;
    const float var = fmaxf(sq * inv_rows - mean * mean, 0.f);
    const float rstd = 1.0f / sqrtf(var + 1e-5f);
    const float sv = g[col] * rstd;
    s[col] = sv;
    t[col] = b[col] - mean * sv;
}

// ---------------------------------------------------------------------------
// Chunked-parallel mamba scan, v8: e-paired lanes.
//  - lane = n (16 lanes/chunk); each lane carries BOTH e-states (h0,h1):
//    Bn/Cn fdot2 shared across e, 4-level DPP tree (was 5), gates merged
//    pre-reduction, two independent h-chains per lane (2x ILP).
//  - 32 chunks x 64 steps; combine arrays in-place (Hin overwrites Sa).
//  - LDS 40960 B -> 4 blocks/CU (8 waves each).
// ---------------------------------------------------------------------------
__global__ __launch_bounds__(512, 8) void mamba_scan8(
    const float* __restrict__ Y, _Float16* __restrict__ a2,
    const float* __restrict__ s1, const float* __restrict__ t1,
    const float* __restrict__ Win, const float* __restrict__ convw,
    const float* __restrict__ convb, const float* __restrict__ Wx,
    const float* __restrict__ Wdt, const float* __restrict__ bdt,
    const float* __restrict__ Alog, const float* __restrict__ Dp,
    const float* __restrict__ Wout)
{
    __shared__ __align__(16) float4 pk[SEQL];   // 32 KB (dt0,dt1,xs h2,gate h2)
    __shared__ float Pa[2][NCH][16];            // 4 KB  chunk products per e
    __shared__ float Sa[2][NCH][16];            // 4 KB  chunk states -> Hin

    const int tid = threadIdx.x;
    const int row = blockIdx.x;
    const float* yrow = Y + (size_t)row * SEQL;
    _Float16* a2row = a2 + (size_t)row * SEQL;

    // ---- phase A': steps [4*tid, 4*tid+4) ---------------------------------
    {
        const int l0 = tid * 4;
        float4 ym = {0.f,0.f,0.f,0.f}, sm = {0.f,0.f,0.f,0.f}, tm = {0.f,0.f,0.f,0.f};
        if (tid > 0) {
            ym = *reinterpret_cast<const float4*>(&yrow[l0 - 4]);
            sm = *reinterpret_cast<const float4*>(&s1[l0 - 4]);
            tm = *reinterpret_cast<const float4*>(&t1[l0 - 4]);
        }
        const float4 y0 = *reinterpret_cast<const float4*>(&yrow[l0]);
        const float4 s0 = *reinterpret_cast<const float4*>(&s1[l0]);
        const float4 t0 = *reinterpret_cast<const float4*>(&t1[l0]);

        float ua[8];
        ua[0] = fmaf(sm.x, ym.x, tm.x);
        ua[1] = fmaf(sm.y, ym.y, tm.y);
        ua[2] = fmaf(sm.z, ym.z, tm.z);
        ua[3] = fmaf(sm.w, ym.w, tm.w);
        ua[4] = fmaf(s0.x, y0.x, t0.x);
        ua[5] = fmaf(s0.y, y0.y, t0.y);
        ua[6] = fmaf(s0.z, y0.z, t0.z);
        ua[7] = fmaf(s0.w, y0.w, t0.w);

        const float wi0 = Win[0], wi1 = Win[1];
        const float wz0 = Win[2], wz1 = Win[3];
        const float wo0 = Wout[0], wo1 = Wout[1];
        const float cw00 = convw[0], cw01 = convw[1], cw02 = convw[2], cw03 = convw[3];
        const float cw10 = convw[4], cw11 = convw[5], cw12 = convw[6], cw13 = convw[7];
        const float cb0 = convb[0], cb1 = convb[1];
        const float wx00 = Wx[0], wx01 = Wx[1];
        const float wdt0 = Wdt[0], wdt1 = Wdt[1];
        const float bdt0 = bdt[0], bdt1 = bdt[1];

        #pragma unroll
        for (int j = 0; j < 4; ++j) {
            const float u0 = ua[j + 4], um1 = ua[j + 3], um2 = ua[j + 2], um3 = ua[j + 1];
            const float c0 = fmaf(wi0, cw00 * um3 + cw01 * um2 + cw02 * um1 + cw03 * u0, cb0);
            const float c1 = fmaf(wi1, cw10 * um3 + cw11 * um2 + cw12 * um1 + cw13 * u0, cb1);
            const float xs0 = c0 / (1.f + __expf(-c0));
            const float xs1 = c1 / (1.f + __expf(-c1));
            const float d0 = xs0 * wx00 + xs1 * wx01;
            const float dt0 = __logf(1.f + __expf(fmaf(d0, wdt0, bdt0)));
            const float dt1 = __logf(1.f + __expf(fmaf(d0, wdt1, bdt1)));
            const float z0 = u0 * wz0, z1 = u0 * wz1;
            const float g0 = (z0 / (1.f + __expf(-z0))) * wo0;
            const float g1 = (z1 / (1.f + __expf(-z1))) * wo1;
            float4 rec;
            rec.x = dt0; rec.y = dt1;
            rec.z = packh2(xs0, xs1);
            rec.w = packh2(g0, g1);
            pk[l0 + j] = rec;
        }
    }
    __syncthreads();

    // ---- lane decomposition: chunk = 16 lanes, lane = n -------------------
    const int ch = tid >> 4;       // chunk 0..31
    const int n  = tid & 15;
    const int base = ch * CHUNK;

    const float A0 = -__expf(Alog[n])      * 1.44269504f;  // e=0, * log2(e)
    const float A1 = -__expf(Alog[16 + n]) * 1.44269504f;  // e=1
    h2 wxB2, wxC2;
    wxB2[0] = (_Float16)Wx[(1 + n) * 2 + 0];
    wxB2[1] = (_Float16)Wx[(1 + n) * 2 + 1];
    wxC2[0] = (_Float16)Wx[(17 + n) * 2 + 0];
    wxC2[1] = (_Float16)Wx[(17 + n) * 2 + 1];

    // ---- phase A'': dual local scan, h_in = 0 -----------------------------
    {
        float h0 = 0.f, h1 = 0.f, p0 = 1.f, p1 = 1.f;
        for (int i0 = 0; i0 < CHUNK; i0 += 8) {
            #pragma unroll
            for (int j = 0; j < 8; ++j) {
                const float4 v = pk[base + i0 + j];
                const h2 xs2 = __builtin_bit_cast(h2, v.z);
                const float Bn = __builtin_amdgcn_fdot2(xs2, wxB2, 0.f, false);
                const float xs0 = hext(v.z, 0), xs1 = hext(v.z, 16);
                const float dA0 = __builtin_amdgcn_exp2f(v.x * A0);
                const float dA1 = __builtin_amdgcn_exp2f(v.y * A1);
                h0 = fmaf(h0, dA0, (v.x * xs0) * Bn);
                h1 = fmaf(h1, dA1, (v.y * xs1) * Bn);
                p0 *= dA0; p1 *= dA1;
            }
        }
        Pa[0][ch][n] = p0; Pa[1][ch][n] = p1;
        Sa[0][ch][n] = h0; Sa[1][ch][n] = h1;
    }
    __syncthreads();

    // ---- phase B: serial chunk combine (in-place Hin into Sa) -------------
    if (tid < 32) {
        const int e = tid >> 4, nn = tid & 15;
        float H = 0.f;
        #pragma unroll
        for (int cc = 0; cc < NCH; ++cc) {
            const float Pv = Pa[e][cc][nn];
            const float Sv = Sa[e][cc][nn];
            Sa[e][cc][nn] = H;             // H_in for chunk cc
            H = fmaf(Pv, H, Sv);
        }
    }
    __syncthreads();

    // ---- phase C: seeded dual re-scan + fp16 output -----------------------
    {
        h2 D2h;
        D2h[0] = (_Float16)Dp[0];
        D2h[1] = (_Float16)Dp[1];
        float h0 = Sa[0][ch][n], h1 = Sa[1][ch][n];
        for (int i0 = 0; i0 < CHUNK; i0 += 8) {
            float qs[8];
            #pragma unroll
            for (int j = 0; j < 8; ++j) {
                const float4 v = pk[base + i0 + j];
                const h2 xs2 = __builtin_bit_cast(h2, v.z);
                const h2 gg2 = __builtin_bit_cast(h2, v.w);
                const float Bn = __builtin_amdgcn_fdot2(xs2, wxB2, 0.f, false);
                const float Cn = __builtin_amdgcn_fdot2(xs2, wxC2, 0.f, false);
                const float xs0 = hext(v.z, 0), xs1 = hext(v.z, 16);
                const float g0 = hext(v.w, 0),  g1 = hext(v.w, 16);
                const float dA0 = __builtin_amdgcn_exp2f(v.x * A0);
                const float dA1 = __builtin_amdgcn_exp2f(v.y * A1);
                h0 = fmaf(h0, dA0, (v.x * xs0) * Bn);
                h1 = fmaf(h1, dA1, (v.y * xs1) * Bn);
                float t = h0 * g0;
                t = fmaf(h1, g1, t);
                float q = t * Cn;
                q = dppadd<0xB1>(q);    // xor1
                q = dppadd<0x4E>(q);    // xor2
                q = dppadd<0x141>(q);   // xor4 (row_half_mirror)
                q = dppadd<0x140>(q);   // xor8 (row_mirror) -> 16-lane sum
                const h2 dgh = D2h * gg2;                       // v_pk_mul_f16
                const float dterm = __builtin_amdgcn_fdot2(xs2, dgh, 0.f, false);
                qs[j] = q + dterm;
            }
            if (n == 0) {
                float4 st;
                st.x = __builtin_bit_cast(float, __builtin_amdgcn_cvt_pkrtz(qs[0], qs[1]));
                st.y = __builtin_bit_cast(float, __builtin_amdgcn_cvt_pkrtz(qs[2], qs[3]));
                st.z = __builtin_bit_cast(float, __builtin_amdgcn_cvt_pkrtz(qs[4], qs[5]));
                st.w = __builtin_bit_cast(float, __builtin_amdgcn_cvt_pkrtz(qs[6], qs[7]));
                *reinterpret_cast<float4*>(&a2row[base + i0]) = st;
            }
        }
    }
}

// ---------------------------------------------------------------------------
extern "C" void kernel_launch(void* const* d_in, const int* in_sizes, int n_in,
                              void* d_out, int out_size, void* d_ws, size_t ws_size,
                              hipStream_t stream)
{
    const float* x     = (const float*)d_in[0];
    const float* W1    = (const float*)d_in[1];
    const float* g1    = (const float*)d_in[2];
    const float* b1    = (const float*)d_in[3];
    const float* Win   = (const float*)d_in[4];
    const float* convw = (const float*)d_in[5];
    const float* convb = (const float*)d_in[6];
    const float* Wx    = (const float*)d_in[7];
    const float* Wdt   = (const float*)d_in[8];
    const float* bdt   = (const float*)d_in[9];
    const float* Alog  = (const float*)d_in[10];
    const float* Dp    = (const float*)d_in[11];
    const float* Wout  = (const float*)d_in[12];
    const float* W2    = (const float*)d_in[13];
    const float* g2    = (const float*)d_in[14];
    const float* b2    = (const float*)d_in[15];
    const float* W3    = (const float*)d_in[16];

    unsigned char* base = (unsigned char*)d_ws;   // all regions disjoint
    float* C1 = (float*)(base + 0);               //  8,388,608
    float* P0 = (float*)(base + 8388608);         //  2,097,152
    float* P1 = (float*)(base + 10485760);        //  2,097,152
    float* s1 = (float*)(base + 12582912);        //  8 KB
    float* t1 = (float*)(base + 12591104);        //  8 KB
    float* s2 = (float*)(base + 12599296);        //  2 KB
    float* t2 = (float*)(base + 12601344);        //  2 KB
    float* bnp = (float*)(base + 12615680);       //  524,288 (32 grp x 2 x 2048)
    _Float16* a2  = (_Float16*)(base + 13172736); //  4,194,304
    _Float16* xh  = (_Float16*)(base + 17367040); //  3,670,016
    _Float16* w1h = (_Float16*)(base + 21037056); //  7,340,032
    _Float16* w2h = (_Float16*)(base + 28377088); //  2,097,152
    _Float16* w3h = (_Float16*)(base + 30474240); //    262,144
    _Float16* h3h = (_Float16*)(base + 30736384); //  1,048,576  (end ~31.8 MB)

    // 1) all fp32->fp16 conversions in one grid-filling dispatch
    cvt_all<<<3840, 256, 0, stream>>>(x, W1, W2, W3, xh, w1h, w2h, w3h);

    // 2) GEMM1: C1 = x @ W1^T ; fused BN1 partials into epilogue
    gemm_f16<<<dim3(32, 16, 1), 256, 0, stream>>>(
        xh, w1h, C1, 2048, 1792, 28, 0, bnp, 2048);

    // 3) BN1 finalize (32 partial groups)
    bn_fin<<<8, 256, 0, stream>>>(bnp, 32, 2048, 1.0f / 1024.f, g1, b1, s1, t1);

    // 4) mamba scan: reads C1, writes a2 (fp16)
    mamba_scan8<<<1024, 512, 0, stream>>>(C1, a2, s1, t1, Win, convw, convb,
                                          Wx, Wdt, bdt, Alog, Dp, Wout);

    // 5) GEMM2 (split-K=2): P0/P1 = a2 @ W2^T  (1024x512, K=2048)
    gemm_f16<<<dim3(8, 16, 2), 256, 0, stream>>>(
        a2, w2h, P0, 512, 2048, 16, (size_t)1024 * 512, nullptr, 0);

    // 6) BN2 stats over P0+P1 (split-K partials summed before squaring)
    bn_part<<<dim3(8, 16), 256, 0, stream>>>(P0, P1, 64, 512, bnp);
    bn_fin<<<2, 256, 0, stream>>>(bnp, 16, 512, 1.0f / 1024.f, g2, b2, s2, t2);

    // 7) h3 = relu(bn2(P0+P1)) -> fp16
    cvt_bnrelu<<<512, 256, 0, stream>>>(P0, P1, s2, t2, h3h);

    // 8) GEMM3: d_out = h3 @ W3^T  (1024x256, K=512)
    gemm_f16<<<dim3(4, 16, 1), 256, 0, stream>>>(
        h3h, w3h, (float*)d_out, 256, 512, 8, 0, nullptr, 0);
}